// Round 5
// baseline (523.615 us; speedup 1.0000x reference)
//
#include <hip/hip_runtime.h>

#define DIM 768
#define NBLK 4
#define BS 192
#define BATCH 8
#define HH 64
#define WW 64
#define KH 33                  // W/2+1 bins
#define NPTS (BATCH*HH*KH)     // 16896 frequency points
#define TWOPI_OVER_64 0.0981747704246810387f
#define LROW 200               // mix LDS row stride in bf16
#define WSZ (NBLK*BS*BS)

typedef __attribute__((ext_vector_type(8))) short short8;
typedef __attribute__((ext_vector_type(4))) short short4v;
typedef __attribute__((ext_vector_type(4))) float floatx4;
typedef __attribute__((ext_vector_type(4))) unsigned int uint4v;

static __device__ __forceinline__ short f2bs(float f) {
  union { float f; unsigned int i; } v; v.f = f;
  unsigned int x = v.i;
  return (short)((x + 0x7fffu + ((x >> 16) & 1u)) >> 16);
}
static __device__ __forceinline__ float bs2f(short s) {
  union { unsigned int i; float f; } v; v.i = ((unsigned int)(unsigned short)s) << 16; return v.f;
}

// async global->LDS, 16B per lane; lds dest must be wave-uniform base.
#define GLD16(gp, lp) \
  __builtin_amdgcn_global_load_lds( \
      (const __attribute__((address_space(1))) unsigned int*)(gp), \
      (__attribute__((address_space(3))) unsigned int*)(lp), 16, 0, 0)

// ---------------------------------------------------------------------------
// Kernel C: convert X (fp32) -> Xb (bf16), RNE.
// ---------------------------------------------------------------------------
__global__ __launch_bounds__(256) void k_convx(
    const float* __restrict__ X, short* __restrict__ Xb)
{
  const int i = blockIdx.x * 256 + threadIdx.x;
  const float4* X4 = (const float4*)X;
  #pragma unroll
  for (int it = 0; it < 12; ++it) {
    const int idx = i + it * (2048 * 256);
    const float4 v = X4[idx];
    short4v p = { f2bs(v.x), f2bs(v.y), f2bs(v.z), f2bs(v.w) };
    *(short4v*)&Xb[(size_t)idx * 4] = p;
  }
}

// convert bias_w (768x768 fp32) -> bf16
__global__ __launch_bounds__(256) void k_convw(
    const float* __restrict__ W, short* __restrict__ Wb)
{
  const int idx = blockIdx.x * 256 + threadIdx.x;   // 147456 quads
  const float4 v = ((const float4*)W)[idx];
  short4v p = { f2bs(v.x), f2bs(v.y), f2bs(v.z), f2bs(v.w) };
  *(short4v*)&Wb[(size_t)idx * 4] = p;
}

// ---------------------------------------------------------------------------
// Kernel 1: bias GEMM via global_load_lds on pre-converted bf16.
// Bias[m,n] = bf16( sum_k Xb[m,k]*Wb[n,k] + bb[n] )   (final add in k_irfft)
// ---------------------------------------------------------------------------
__global__ __launch_bounds__(256) void k_bias_gemm3(
    const short* __restrict__ Xb, const short* __restrict__ Wb,
    const float* __restrict__ bb, short* __restrict__ Bias)
{
  __shared__ short As[128 * 32];   // [row][k] rows of 64B
  __shared__ short Bs[128 * 32];
  const int t = threadIdx.x;
  const int wave = t >> 6, lane = t & 63;
  const int qm = lane & 15, quad = lane >> 4;
  const int wr = (wave >> 1) * 64;
  const int wc = (wave & 1) * 64;
  const int m0 = blockIdx.x * 128, n0 = blockIdx.y * 128;

  floatx4 acc[4][4];
  const floatx4 zero = {0.f, 0.f, 0.f, 0.f};
  #pragma unroll
  for (int ms = 0; ms < 4; ++ms)
    #pragma unroll
    for (int ns = 0; ns < 4; ++ns) acc[ms][ns] = zero;

  const int r0 = t >> 2,        kq0 = (t & 3) * 8;
  const int r1 = (t + 256) >> 2;
  const short* gA0 = &Xb[(size_t)(m0 + r0) * DIM + kq0];
  const short* gA1 = &Xb[(size_t)(m0 + r1) * DIM + kq0];
  const short* gB0 = &Wb[(size_t)(n0 + r0) * DIM + kq0];
  const short* gB1 = &Wb[(size_t)(n0 + r1) * DIM + kq0];
  short* lA0 = &As[wave * 512];
  short* lA1 = &As[wave * 512 + 2048];
  short* lB0 = &Bs[wave * 512];
  short* lB1 = &Bs[wave * 512 + 2048];

  #pragma unroll 1
  for (int k0 = 0; k0 < DIM; k0 += 32) {
    __syncthreads();
    GLD16(gA0 + k0, lA0);
    GLD16(gA1 + k0, lA1);
    GLD16(gB0 + k0, lB0);
    GLD16(gB1 + k0, lB1);
    __syncthreads();

    short8 af[4], bf[4];
    #pragma unroll
    for (int ms = 0; ms < 4; ++ms)
      af[ms] = *(const short8*)&As[(wr + ms*16 + qm) * 32 + quad * 8];
    #pragma unroll
    for (int ns = 0; ns < 4; ++ns)
      bf[ns] = *(const short8*)&Bs[(wc + ns*16 + qm) * 32 + quad * 8];
    #pragma unroll
    for (int ms = 0; ms < 4; ++ms)
      #pragma unroll
      for (int ns = 0; ns < 4; ++ns)
        acc[ms][ns] = __builtin_amdgcn_mfma_f32_16x16x32_bf16(af[ms], bf[ns], acc[ms][ns], 0, 0, 0);
  }

  #pragma unroll
  for (int ns = 0; ns < 4; ++ns) {
    const int col = n0 + wc + ns*16 + qm;
    const float bias = bb[col];
    #pragma unroll
    for (int ms = 0; ms < 4; ++ms)
      #pragma unroll
      for (int r = 0; r < 4; ++r) {
        const int row = m0 + wr + ms*16 + quad*4 + r;
        Bias[(size_t)row * DIM + col] = f2bs(acc[ms][ns][r] + bias);
      }
  }
}

// ---------------------------------------------------------------------------
// Kernel 2: row rFFT along w as MFMA GEMM (bf16 in, bf16 out).
// ---------------------------------------------------------------------------
__global__ __launch_bounds__(256) void k_rfft_w_mfma(
    const short* __restrict__ Xb,
    short* __restrict__ Sr, short* __restrict__ Si)
{
  __shared__ short Lx[96 * 72];   // [c][w], row stride 72 shorts
  const int t = threadIdx.x;
  const int wave = t >> 6, lane = t & 63;
  const int qm = lane & 15, quad = lane >> 4;
  const int bh = blockIdx.x;
  const int c0 = blockIdx.y * 96;
  const size_t xbase = (size_t)bh * (WW*DIM);
  const size_t obase = (size_t)bh * (KH*DIM);

  // issue staging loads first
  const int hd = t & 31;              // w-pair
  const int c4b = t >> 5;             // 0..7
  short4v ra[3], rb[3];
  #pragma unroll
  for (int it = 0; it < 3; ++it) {
    const int c4 = c4b + it * 8;      // 0..23
    const size_t g0 = xbase + (size_t)(2*hd) * DIM + c0 + c4 * 4;
    ra[it] = *(const short4v*)&Xb[g0];
    rb[it] = *(const short4v*)&Xb[g0 + DIM];
  }

  // twiddles while loads fly: m=k (qm), k=w; e^{-i}, hi/lo split
  short8 Trh[2], Trl[2], Tih[2], Til[2];
  const int krow = wave * 16 + qm;
  #pragma unroll
  for (int kk = 0; kk < 2; ++kk) {
    #pragma unroll
    for (int j = 0; j < 8; ++j) {
      const int w = quad * 8 + j + kk * 32;
      const int ph = (krow * w) & 63;
      float s, c;
      sincosf((float)ph * TWOPI_OVER_64, &s, &c);
      const float tr = c, ti = -s;
      const short trh = f2bs(tr);
      const short tih = f2bs(ti);
      Trh[kk][j] = trh;  Trl[kk][j] = f2bs(tr - bs2f(trh));
      Tih[kk][j] = tih;  Til[kk][j] = f2bs(ti - bs2f(tih));
    }
  }

  // write staged data -> LDS transposed [c][w] bf16 (w pairs packed in dwords)
  #pragma unroll
  for (int it = 0; it < 3; ++it) {
    const int c4 = c4b + it * 8;
    #pragma unroll
    for (int e = 0; e < 4; ++e) {
      const int d = (c4*4 + e) * 36 + hd;
      ((unsigned*)Lx)[d] = (unsigned)(unsigned short)ra[it][e] |
                           ((unsigned)(unsigned short)rb[it][e] << 16);
    }
  }
  __syncthreads();

  if (wave < 3) {
    const floatx4 zero = {0.f, 0.f, 0.f, 0.f};
    #pragma unroll 1
    for (int ct = 0; ct < 6; ++ct) {
      floatx4 Cr = zero, Ci = zero;
      #pragma unroll
      for (int kk = 0; kk < 2; ++kk) {
        const int a = (ct*16 + qm) * 72 + kk*32 + quad*8;
        const short8 xv = *(const short8*)&Lx[a];
        Cr = __builtin_amdgcn_mfma_f32_16x16x32_bf16(Trh[kk], xv, Cr, 0,0,0);
        Cr = __builtin_amdgcn_mfma_f32_16x16x32_bf16(Trl[kk], xv, Cr, 0,0,0);
        Ci = __builtin_amdgcn_mfma_f32_16x16x32_bf16(Tih[kk], xv, Ci, 0,0,0);
        Ci = __builtin_amdgcn_mfma_f32_16x16x32_bf16(Til[kk], xv, Ci, 0,0,0);
      }
      #pragma unroll
      for (int r = 0; r < 4; ++r) {
        const int ko = wave*16 + quad*4 + r;
        if (ko < KH) {
          const size_t o = obase + (size_t)ko * DIM + c0 + ct*16 + qm;
          Sr[o] = f2bs(Cr[r]);
          Si[o] = f2bs(Ci[r]);
        }
      }
    }
  }
}

// ---------------------------------------------------------------------------
// Kernel P: transpose + convert mixing weights to bf16 B^T fragments.
// Slots: 0=W1R 1=W1I 2=W2R 3=W2IN(-W2I)   (W1IN synthesized by sign-flip)
// ---------------------------------------------------------------------------
__global__ __launch_bounds__(256) void k_prep_w(
    const float* __restrict__ w1, const float* __restrict__ w2,
    short* __restrict__ Wout)
{
  const int arr = blockIdx.y;           // 0..3
  const int i = blockIdx.x * 256 + threadIdx.x;
  const int nb = i / (BS*BS);
  const int rem = i % (BS*BS);
  const int n = rem / BS;
  const int d = rem % BS;
  const float* src = (arr < 2) ? w1 : w2;
  const int j = arr & 1;
  const float s = (arr == 3) ? -1.f : 1.f;
  const float v = s * src[((size_t)(j*NBLK + nb) * BS + d) * BS + n];
  Wout[(size_t)arr * WSZ + i] = f2bs(v);
}

// ---------------------------------------------------------------------------
// Kernel P2: composite layer-2 weights so i2 depends only on (r1,i1):
//   i2 = r1@(W2R.W2I) + i1@(W2R - W2I.W2I) + (b2i + b2r@W2I)
// Slots: 4=W2RI frag, 5=W2X frag; b2x float vector.
// ---------------------------------------------------------------------------
__global__ __launch_bounds__(256) void k_prep_w2(
    const float* __restrict__ w2, const float* __restrict__ b2,
    short* __restrict__ Wout, float* __restrict__ b2x)
{
  const int i = blockIdx.x * 256 + threadIdx.x;   // 0..4*192*192-1
  const int n = i % BS;
  const int d = (i / BS) % BS;                    // wave-uniform (192 = 3*64)
  const int nb = i / (BS*BS);
  const float* R = w2 + (size_t)nb * BS * BS;            // w2[0][nb][d][k]
  const float* I = w2 + ((size_t)NBLK + nb) * BS * BS;   // w2[1][nb][d][k]
  const float* br = b2 + nb * BS;
  float ri = 0.f, ii = 0.f, bx = 0.f;
  #pragma unroll 4
  for (int m = 0; m < BS; ++m) {
    const float win = I[m*BS + n];      // coalesced over n
    ri += R[d*BS + m] * win;            // scalar (wave-uniform)
    ii += I[d*BS + m] * win;
    bx += br[m] * win;
  }
  const size_t o = ((size_t)nb * BS + n) * BS + d;   // frag layout [nb][n][d]
  Wout[(size_t)4 * WSZ + o] = f2bs(ri);
  Wout[(size_t)5 * WSZ + o] = f2bs(R[d*BS + n] - ii);
  if (d == 0) b2x[nb * BS + n] = b2[(NBLK + nb) * BS + n] + bx;
}

// ---------------------------------------------------------------------------
// Kernel F (v5): FUSED fft_h -> MLP -> ifft_h, 512 threads / 8 waves.
// Same 55,296 B padded-72 LDS union, same (b,k,nb) tile, but the per-phase
// work is split across 2x the waves:
//   DFT phases: w4 = wave&3 owns output rows w4*16+qm; half = wave>>2 owns
//               channel tiles ct = half*6 .. half*6+5   (Fr/Fi 12 -> 6)
//   mix phases: w4 owns cols w4*48+nt*16; half owns rows ms = half*2+{0,1}
// 4 waves/SIMD resident (was 2) -> dependency chains overlap at the
// scheduler; per-wave critical path halves.
// ---------------------------------------------------------------------------
__global__ __launch_bounds__(512) void k_fmix(
    short* __restrict__ Sr, short* __restrict__ Si,
    const short* __restrict__ WT,
    const float* __restrict__ b1, const float* __restrict__ b2,
    const float* __restrict__ b2x)
{
  __shared__ short U[2 * 192 * 72];          // 55,296 B union
  short* Ldr = U;                             // [192][72]
  short* Ldi = U + 192 * 72;
  short* Amr = U;                             // [64][LROW]
  short* Ami = U + 64 * LROW;

  const int t = threadIdx.x;
  const int wave = t >> 6, lane = t & 63;
  const int w4 = wave & 3, half = wave >> 2;
  const int qm = lane & 15, quad = lane >> 4;
  const int bk = blockIdx.x;
  const int b = bk / KH, k = bk % KH;
  const int nb = blockIdx.y;
  const int c0 = nb * BS;
  const size_t hstride = (size_t)KH * DIM;
  const size_t base = ((size_t)b * HH * KH + k) * DIM;

  // ---- issue phase-1 staging loads FIRST. 768 slots over 512 threads:
  // slot i: hd = i&31 (h-pair), c8 = i>>5 (0..23, 8 channels each)
  const int hd0 = t & 31;
  const int c80 = t >> 5;             // 0..15
  const int c81 = c80 + 16;           // 16..23 (only t<256)
  const bool has1 = (t < 256);
  short8 ra0, rb0, ia0, ib0, ra1, rb1, ia1, ib1;
  {
    const size_t g0 = base + (size_t)(2*hd0) * hstride + c0 + c80 * 8;
    ra0 = *(const short8*)&Sr[g0];
    rb0 = *(const short8*)&Sr[g0 + hstride];
    ia0 = *(const short8*)&Si[g0];
    ib0 = *(const short8*)&Si[g0 + hstride];
  }
  if (has1) {
    const size_t g1 = base + (size_t)(2*hd0) * hstride + c0 + c81 * 8;
    ra1 = *(const short8*)&Sr[g1];
    rb1 = *(const short8*)&Sr[g1 + hstride];
    ia1 = *(const short8*)&Si[g1];
    ib1 = *(const short8*)&Si[g1 + hstride];
  }

  // ---- twiddles while loads fly: C=cos S=sin SN=-sin, hi/lo split
  short8 Ch[2], Cl[2], Sh[2], Sl[2], SNh[2], SNl[2];
  const int hp = w4 * 16 + qm;
  #pragma unroll
  for (int kk = 0; kk < 2; ++kk)
    #pragma unroll
    for (int j = 0; j < 8; ++j) {
      const int h = quad*8 + j + kk*32;
      const int ph = (hp * h) & 63;
      float s, c;
      sincosf((float)ph * TWOPI_OVER_64, &s, &c);
      const short ch = f2bs(c), sh = f2bs(s);
      Ch[kk][j] = ch;  Cl[kk][j] = f2bs(c - bs2f(ch));
      Sh[kk][j] = sh;  Sl[kk][j] = f2bs(s - bs2f(sh));
      SNh[kk][j] = (short)(sh ^ (short)0x8000);
      SNl[kk][j] = (short)(Sl[kk][j] ^ (short)0x8000);
    }

  // ---- phase 1 writes: Ld [c][h] padded-72, h-pairs packed in dwords
  #pragma unroll
  for (int e = 0; e < 8; ++e) {
    const int d = (c80*8 + e) * 36 + hd0;
    ((unsigned*)Ldr)[d] = (unsigned)(unsigned short)ra0[e] |
                          ((unsigned)(unsigned short)rb0[e] << 16);
    ((unsigned*)Ldi)[d] = (unsigned)(unsigned short)ia0[e] |
                          ((unsigned)(unsigned short)ib0[e] << 16);
  }
  if (has1) {
    #pragma unroll
    for (int e = 0; e < 8; ++e) {
      const int d = (c81*8 + e) * 36 + hd0;
      ((unsigned*)Ldr)[d] = (unsigned)(unsigned short)ra1[e] |
                            ((unsigned)(unsigned short)rb1[e] << 16);
      ((unsigned*)Ldi)[d] = (unsigned)(unsigned short)ia1[e] |
                            ((unsigned)(unsigned short)ib1[e] << 16);
    }
  }
  __syncthreads();

  // ---- phase 2: forward DFT along h (ti = -s), 6 cts per wave
  const floatx4 zero = {0.f, 0.f, 0.f, 0.f};
  floatx4 Fr[6], Fi[6];
  #pragma unroll
  for (int j = 0; j < 6; ++j) { Fr[j] = zero; Fi[j] = zero; }
  #pragma unroll
  for (int j = 0; j < 6; ++j) {
    const int ct = half * 6 + j;
    #pragma unroll
    for (int kk = 0; kk < 2; ++kk) {
      const int a = (ct*16 + qm) * 72 + kk*32 + quad*8;
      const short8 sr = *(const short8*)&Ldr[a];
      const short8 si = *(const short8*)&Ldi[a];
      Fr[j] = __builtin_amdgcn_mfma_f32_16x16x32_bf16(Ch[kk],  sr, Fr[j], 0,0,0);
      Fr[j] = __builtin_amdgcn_mfma_f32_16x16x32_bf16(Cl[kk],  sr, Fr[j], 0,0,0);
      Fr[j] = __builtin_amdgcn_mfma_f32_16x16x32_bf16(Sh[kk],  si, Fr[j], 0,0,0);
      Fr[j] = __builtin_amdgcn_mfma_f32_16x16x32_bf16(Sl[kk],  si, Fr[j], 0,0,0);
      Fi[j] = __builtin_amdgcn_mfma_f32_16x16x32_bf16(SNh[kk], sr, Fi[j], 0,0,0);
      Fi[j] = __builtin_amdgcn_mfma_f32_16x16x32_bf16(SNl[kk], sr, Fi[j], 0,0,0);
      Fi[j] = __builtin_amdgcn_mfma_f32_16x16x32_bf16(Ch[kk],  si, Fi[j], 0,0,0);
      Fi[j] = __builtin_amdgcn_mfma_f32_16x16x32_bf16(Cl[kk],  si, Fi[j], 0,0,0);
    }
  }
  __syncthreads();   // Ld dead; U becomes Am

  // ---- phase 3: write mix input = F * (1/64) (exact scale), bf16 -> Am
  #pragma unroll
  for (int j = 0; j < 6; ++j) {
    const int ct = half * 6 + j;
    #pragma unroll
    for (int r = 0; r < 4; ++r) {
      const int row = w4*16 + quad*4 + r;      // h-point = mix row
      const int c = ct*16 + qm;
      Amr[row * LROW + c] = f2bs(Fr[j][r] * 0.015625f);
      Ami[row * LROW + c] = f2bs(Fi[j][r] * 0.015625f);
    }
  }
  __syncthreads();

  // ---- mix setup
  const short* W1R  = WT;
  const short* W1I  = WT + 1 * (size_t)WSZ;
  const short* W2R  = WT + 2 * (size_t)WSZ;
  const short* W2IN = WT + 3 * (size_t)WSZ;
  const short* W2RI = WT + 4 * (size_t)WSZ;
  const short* W2X  = WT + 5 * (size_t)WSZ;

  int nl[3];
  size_t wb[3];
  #pragma unroll
  for (int nt = 0; nt < 3; ++nt) {
    nl[nt] = w4 * 48 + nt * 16 + qm;
    wb[nt] = (size_t)(c0 + nl[nt]) * BS + quad * 8;
  }

  // ---- phase 4: layer 1; rows split by half (ms = half*2 + msl)
  floatx4 aR[2][3], aI[2][3];
  #pragma unroll
  for (int msl = 0; msl < 2; ++msl)
    #pragma unroll
    for (int nt = 0; nt < 3; ++nt) { aR[msl][nt] = zero; aI[msl][nt] = zero; }

  #pragma unroll 1
  for (int k0 = 0; k0 < BS; k0 += 32) {
    short8 xr[2], xi[2];
    #pragma unroll
    for (int msl = 0; msl < 2; ++msl) {
      const int a = ((half*2 + msl)*16 + qm) * LROW + k0 + quad * 8;
      xr[msl] = *(const short8*)&Amr[a];
      xi[msl] = *(const short8*)&Ami[a];
    }
    #pragma unroll
    for (int nt = 0; nt < 3; ++nt) {
      const short8 br = *(const short8*)&W1R[wb[nt] + k0];
      const short8 bi = *(const short8*)&W1I[wb[nt] + k0];
      short8 bin;                                   // -W1I via sign-bit flip
      *(uint4v*)&bin = *(const uint4v*)&bi ^ 0x80008000u;
      #pragma unroll
      for (int msl = 0; msl < 2; ++msl) {
        aR[msl][nt] = __builtin_amdgcn_mfma_f32_16x16x32_bf16(xr[msl], br,  aR[msl][nt], 0,0,0);
        aR[msl][nt] = __builtin_amdgcn_mfma_f32_16x16x32_bf16(xi[msl], bin, aR[msl][nt], 0,0,0);
        aI[msl][nt] = __builtin_amdgcn_mfma_f32_16x16x32_bf16(xr[msl], bi,  aI[msl][nt], 0,0,0);
        aI[msl][nt] = __builtin_amdgcn_mfma_f32_16x16x32_bf16(xi[msl], br,  aI[msl][nt], 0,0,0);
      }
    }
  }
  __syncthreads();
  #pragma unroll
  for (int nt = 0; nt < 3; ++nt) {
    const float b1r = b1[nb * BS + nl[nt]];
    const float b1i = b1[(NBLK + nb) * BS + nl[nt]];
    #pragma unroll
    for (int msl = 0; msl < 2; ++msl)
      #pragma unroll
      for (int r = 0; r < 4; ++r) {
        const int row = (half*2 + msl)*16 + quad*4 + r;
        Amr[row * LROW + nl[nt]] = f2bs(fmaxf(aR[msl][nt][r] + b1r, 0.f));
        Ami[row * LROW + nl[nt]] = f2bs(fmaxf(aI[msl][nt][r] + b1i, 0.f));
      }
  }
  __syncthreads();

  // ---- phase 5: layer 2 merged: r2 = r1@W2R + i1@W2IN; i2 = r1@W2RI + i1@W2X
  floatx4 c2r[2][3], c2i[2][3];
  #pragma unroll
  for (int msl = 0; msl < 2; ++msl)
    #pragma unroll
    for (int nt = 0; nt < 3; ++nt) { c2r[msl][nt] = zero; c2i[msl][nt] = zero; }

  #pragma unroll 1
  for (int k0 = 0; k0 < BS; k0 += 32) {
    short8 r1[2], i1[2];
    #pragma unroll
    for (int msl = 0; msl < 2; ++msl) {
      const int a = ((half*2 + msl)*16 + qm) * LROW + k0 + quad * 8;
      r1[msl] = *(const short8*)&Amr[a];
      i1[msl] = *(const short8*)&Ami[a];
    }
    #pragma unroll
    for (int nt = 0; nt < 3; ++nt) {
      const short8 w_r  = *(const short8*)&W2R [wb[nt] + k0];
      const short8 w_in = *(const short8*)&W2IN[wb[nt] + k0];
      const short8 w_ri = *(const short8*)&W2RI[wb[nt] + k0];
      const short8 w_x  = *(const short8*)&W2X [wb[nt] + k0];
      #pragma unroll
      for (int msl = 0; msl < 2; ++msl) {
        c2r[msl][nt] = __builtin_amdgcn_mfma_f32_16x16x32_bf16(r1[msl], w_r,  c2r[msl][nt], 0,0,0);
        c2r[msl][nt] = __builtin_amdgcn_mfma_f32_16x16x32_bf16(i1[msl], w_in, c2r[msl][nt], 0,0,0);
        c2i[msl][nt] = __builtin_amdgcn_mfma_f32_16x16x32_bf16(r1[msl], w_ri, c2i[msl][nt], 0,0,0);
        c2i[msl][nt] = __builtin_amdgcn_mfma_f32_16x16x32_bf16(i1[msl], w_x,  c2i[msl][nt], 0,0,0);
      }
    }
  }
  __syncthreads();   // Am dead; U becomes Ld again

  // ---- phase 6: stage r2+b2r, i2+b2x -> Ld [c][h] padded-72 bf16
  #pragma unroll
  for (int nt = 0; nt < 3; ++nt) {
    const float b2r = b2 [nb * BS + nl[nt]];
    const float bxi = b2x[nb * BS + nl[nt]];
    const int c = nl[nt];
    #pragma unroll
    for (int msl = 0; msl < 2; ++msl)
      #pragma unroll
      for (int r = 0; r < 4; ++r) {
        const int row = (half*2 + msl)*16 + quad*4 + r;    // h
        Ldr[c * 72 + row] = f2bs(c2r[msl][nt][r] + b2r);
        Ldi[c * 72 + row] = f2bs(c2i[msl][nt][r] + bxi);
      }
  }
  __syncthreads();

  // ---- phase 7: inverse DFT (ti = +s) -> global bf16, 6 cts per wave
  #pragma unroll 1
  for (int j = 0; j < 6; ++j) {
    const int ct = half * 6 + j;
    floatx4 Cr = zero, Ci = zero;
    #pragma unroll
    for (int kk = 0; kk < 2; ++kk) {
      const int a = (ct*16 + qm) * 72 + kk*32 + quad*8;
      const short8 gr = *(const short8*)&Ldr[a];
      const short8 gi = *(const short8*)&Ldi[a];
      Cr = __builtin_amdgcn_mfma_f32_16x16x32_bf16(Ch[kk],  gr, Cr, 0,0,0);
      Cr = __builtin_amdgcn_mfma_f32_16x16x32_bf16(Cl[kk],  gr, Cr, 0,0,0);
      Cr = __builtin_amdgcn_mfma_f32_16x16x32_bf16(SNh[kk], gi, Cr, 0,0,0);
      Cr = __builtin_amdgcn_mfma_f32_16x16x32_bf16(SNl[kk], gi, Cr, 0,0,0);
      Ci = __builtin_amdgcn_mfma_f32_16x16x32_bf16(Sh[kk],  gr, Ci, 0,0,0);
      Ci = __builtin_amdgcn_mfma_f32_16x16x32_bf16(Sl[kk],  gr, Ci, 0,0,0);
      Ci = __builtin_amdgcn_mfma_f32_16x16x32_bf16(Ch[kk],  gi, Ci, 0,0,0);
      Ci = __builtin_amdgcn_mfma_f32_16x16x32_bf16(Cl[kk],  gi, Ci, 0,0,0);
    }
    #pragma unroll
    for (int r = 0; r < 4; ++r) {
      const int hpo = w4*16 + quad*4 + r;
      const size_t o = base + (size_t)hpo * hstride + c0 + ct*16 + qm;
      Sr[o] = f2bs(Cr[r]);
      Si[o] = f2bs(Ci[r]);
    }
  }
}

// ---------------------------------------------------------------------------
// Kernel 6: c2r inverse along k as MFMA GEMM + bias add (bf16 in, fp32 out).
// ---------------------------------------------------------------------------
__global__ __launch_bounds__(256) void k_irfft_w_mfma(
    const short* __restrict__ Sr, const short* __restrict__ Si,
    const short* __restrict__ Bias, float* __restrict__ out)
{
  __shared__ short Lr[96 * 72];   // [c][k], zero-padded k>=33
  __shared__ short Li[96 * 72];
  const int t = threadIdx.x;
  const int wave = t >> 6, lane = t & 63;
  const int qm = lane & 15, quad = lane >> 4;
  const int bh = blockIdx.x;
  const int c0 = blockIdx.y * 96;
  const size_t gbase = (size_t)bh * (KH*DIM);
  const size_t obase = (size_t)bh * (WW*DIM);

  // issue staging loads first
  const int hd = t & 31;              // k-pair: 2hd, 2hd+1
  const int c4b = t >> 5;
  short4v ra[3], rb[3], ia[3], ib[3];
  #pragma unroll
  for (int it = 0; it < 3; ++it) {
    const int c4 = c4b + it * 8;
    const int ka = 2*hd, kb = 2*hd + 1;
    short4v z = {0,0,0,0};
    ra[it] = z; rb[it] = z; ia[it] = z; ib[it] = z;
    if (ka < KH) {
      const size_t g0 = gbase + (size_t)ka * DIM + c0 + c4 * 4;
      ra[it] = *(const short4v*)&Sr[g0];
      ia[it] = *(const short4v*)&Si[g0];
    }
    if (kb < KH) {
      const size_t g1 = gbase + (size_t)kb * DIM + c0 + c4 * 4;
      rb[it] = *(const short4v*)&Sr[g1];
      ib[it] = *(const short4v*)&Si[g1];
    }
  }

  // twiddles while loads fly
  short8 Arh[2], Arl[2], Aih[2], Ail[2];
  const int wrow = wave * 16 + qm;
  #pragma unroll
  for (int kk = 0; kk < 2; ++kk) {
    #pragma unroll
    for (int j = 0; j < 8; ++j) {
      const int k = quad * 8 + j + kk * 32;
      float ar = 0.f, ai = 0.f;
      if (k < KH) {
        const int ph = (wrow * k) & 63;
        float s, c;
        sincosf((float)ph * TWOPI_OVER_64, &s, &c);
        const float ck = (k == 0 || k == 32) ? (1.0f/64.0f) : (2.0f/64.0f);
        ar = ck * c;
        ai = -ck * s;
      }
      const short arh = f2bs(ar);
      const short aih = f2bs(ai);
      Arh[kk][j] = arh;  Arl[kk][j] = f2bs(ar - bs2f(arh));
      Aih[kk][j] = aih;  Ail[kk][j] = f2bs(ai - bs2f(aih));
    }
  }

  // write staged data -> LDS
  #pragma unroll
  for (int it = 0; it < 3; ++it) {
    const int c4 = c4b + it * 8;
    #pragma unroll
    for (int e = 0; e < 4; ++e) {
      const int d = (c4*4 + e) * 36 + hd;
      ((unsigned*)Lr)[d] = (unsigned)(unsigned short)ra[it][e] |
                           ((unsigned)(unsigned short)rb[it][e] << 16);
      ((unsigned*)Li)[d] = (unsigned)(unsigned short)ia[it][e] |
                           ((unsigned)(unsigned short)ib[it][e] << 16);
    }
  }
  __syncthreads();

  const floatx4 zero = {0.f, 0.f, 0.f, 0.f};
  #pragma unroll 1
  for (int ct = 0; ct < 6; ++ct) {
    floatx4 C = zero;
    #pragma unroll
    for (int kk = 0; kk < 2; ++kk) {
      const int a = (ct*16 + qm) * 72 + kk*32 + quad*8;
      const short8 gr = *(const short8*)&Lr[a];
      const short8 gi = *(const short8*)&Li[a];
      C = __builtin_amdgcn_mfma_f32_16x16x32_bf16(Arh[kk], gr, C, 0,0,0);
      C = __builtin_amdgcn_mfma_f32_16x16x32_bf16(Arl[kk], gr, C, 0,0,0);
      C = __builtin_amdgcn_mfma_f32_16x16x32_bf16(Aih[kk], gi, C, 0,0,0);
      C = __builtin_amdgcn_mfma_f32_16x16x32_bf16(Ail[kk], gi, C, 0,0,0);
    }
    #pragma unroll
    for (int r = 0; r < 4; ++r) {
      const int w = wave*16 + quad*4 + r;
      const size_t o = obase + (size_t)w * DIM + c0 + ct*16 + qm;
      out[o] = C[r] + bs2f(Bias[o]);    // single fp32 store, no RMW
    }
  }
}

// ---------------------------------------------------------------------------
extern "C" void kernel_launch(void* const* d_in, const int* in_sizes, int n_in,
                              void* d_out, int out_size, void* d_ws, size_t ws_size,
                              hipStream_t stream) {
  const float* x  = (const float*)d_in[0];
  const float* w1 = (const float*)d_in[1];
  const float* b1 = (const float*)d_in[2];
  const float* w2 = (const float*)d_in[3];
  const float* b2 = (const float*)d_in[4];
  const float* bw = (const float*)d_in[5];
  const float* bb = (const float*)d_in[6];
  float* out = (float*)d_out;

  short* Sr = (short*)d_ws;
  short* Si = Sr + (size_t)NPTS * DIM;
  short* WT = Si + (size_t)NPTS * DIM;
  short* Xb = WT + (size_t)6 * WSZ;
  short* Wb = Xb + (size_t)BATCH * HH * WW * DIM;
  short* Bias = Wb + (size_t)DIM * DIM;
  float* b2x = (float*)(Bias + (size_t)BATCH * HH * WW * DIM);

  // C) convert X and bias_w to bf16
  k_convx<<<2048, 256, 0, stream>>>(x, Xb);
  k_convw<<<(DIM*DIM/4)/256, 256, 0, stream>>>(bw, Wb);
  // P) transpose+convert mixing weights to bf16 fragments (4 arrays)
  k_prep_w<<<dim3(WSZ/256, 4), 256, 0, stream>>>(w1, w2, WT);
  // P2) composite layer-2 weights + bias for merged real/imag phase
  k_prep_w2<<<dim3(WSZ/256), 256, 0, stream>>>(w2, b2, WT, b2x);
  // 1) bias partial = x @ bias_w^T + bias_b  -> bf16 buffer
  k_bias_gemm3<<<dim3(32768/128, DIM/128), 256, 0, stream>>>(Xb, Wb, bb, Bias);
  // 2) forward rfft along w via MFMA (unnormalized), bf16 out
  k_rfft_w_mfma<<<dim3(BATCH*HH, DIM/96), 256, 0, stream>>>(Xb, Sr, Si);
  // 3-5) FUSED: fft_h -> block MLP -> ifft_h, 8 waves/block
  k_fmix<<<dim3(BATCH*KH, NBLK), 512, 0, stream>>>(Sr, Si, WT, b1, b2, b2x);
  // 6) c2r inverse along k via MFMA + bias add -> final fp32 output
  k_irfft_w_mfma<<<dim3(BATCH*HH, DIM/96), 256, 0, stream>>>(Sr, Si, Bias, out);
}

// Round 6
// 483.702 us; speedup vs baseline: 1.0825x; 1.0825x over previous
//
#include <hip/hip_runtime.h>

#define DIM 768
#define NBLK 4
#define BS 192
#define BATCH 8
#define HH 64
#define WW 64
#define KH 33                  // W/2+1 bins
#define NPTS (BATCH*HH*KH)     // 16896 frequency points
#define TWOPI_OVER_64 0.0981747704246810387f
#define LROW 200               // mix LDS row stride in bf16
#define WSZ (NBLK*BS*BS)

typedef __attribute__((ext_vector_type(8))) short short8;
typedef __attribute__((ext_vector_type(4))) short short4v;
typedef __attribute__((ext_vector_type(4))) float floatx4;
typedef __attribute__((ext_vector_type(4))) unsigned int uint4v;

static __device__ __forceinline__ short f2bs(float f) {
  union { float f; unsigned int i; } v; v.f = f;
  unsigned int x = v.i;
  return (short)((x + 0x7fffu + ((x >> 16) & 1u)) >> 16);
}
static __device__ __forceinline__ float bs2f(short s) {
  union { unsigned int i; float f; } v; v.i = ((unsigned int)(unsigned short)s) << 16; return v.f;
}

// async global->LDS, 16B per lane; lds dest must be wave-uniform base.
#define GLD16(gp, lp) \
  __builtin_amdgcn_global_load_lds( \
      (const __attribute__((address_space(1))) unsigned int*)(gp), \
      (__attribute__((address_space(3))) unsigned int*)(lp), 16, 0, 0)

// ---------------------------------------------------------------------------
// Kernel C: convert X (fp32) -> Xb (bf16), RNE.
// ---------------------------------------------------------------------------
__global__ __launch_bounds__(256) void k_convx(
    const float* __restrict__ X, short* __restrict__ Xb)
{
  const int i = blockIdx.x * 256 + threadIdx.x;
  const float4* X4 = (const float4*)X;
  #pragma unroll
  for (int it = 0; it < 12; ++it) {
    const int idx = i + it * (2048 * 256);
    const float4 v = X4[idx];
    short4v p = { f2bs(v.x), f2bs(v.y), f2bs(v.z), f2bs(v.w) };
    *(short4v*)&Xb[(size_t)idx * 4] = p;
  }
}

// convert bias_w (768x768 fp32) -> bf16
__global__ __launch_bounds__(256) void k_convw(
    const float* __restrict__ W, short* __restrict__ Wb)
{
  const int idx = blockIdx.x * 256 + threadIdx.x;   // 147456 quads
  const float4 v = ((const float4*)W)[idx];
  short4v p = { f2bs(v.x), f2bs(v.y), f2bs(v.z), f2bs(v.w) };
  *(short4v*)&Wb[(size_t)idx * 4] = p;
}

// ---------------------------------------------------------------------------
// Kernel 1 (r2 version): bias GEMM via global_load_lds on bf16.
// out[m,n] = sum_k Xb[m,k]*Wb[n,k] + bb[n]   (fp32 partial, irfft adds)
// ---------------------------------------------------------------------------
__global__ __launch_bounds__(256) void k_bias_gemm3(
    const short* __restrict__ Xb, const short* __restrict__ Wb,
    const float* __restrict__ bb, float* __restrict__ out)
{
  __shared__ short As[128 * 32];   // [row][k] rows of 64B
  __shared__ short Bs[128 * 32];
  const int t = threadIdx.x;
  const int wave = t >> 6, lane = t & 63;
  const int qm = lane & 15, quad = lane >> 4;
  const int wr = (wave >> 1) * 64;
  const int wc = (wave & 1) * 64;
  const int m0 = blockIdx.x * 128, n0 = blockIdx.y * 128;

  floatx4 acc[4][4];
  const floatx4 zero = {0.f, 0.f, 0.f, 0.f};
  #pragma unroll
  for (int ms = 0; ms < 4; ++ms)
    #pragma unroll
    for (int ns = 0; ns < 4; ++ns) acc[ms][ns] = zero;

  const int r0 = t >> 2,        kq0 = (t & 3) * 8;
  const int r1 = (t + 256) >> 2;
  const short* gA0 = &Xb[(size_t)(m0 + r0) * DIM + kq0];
  const short* gA1 = &Xb[(size_t)(m0 + r1) * DIM + kq0];
  const short* gB0 = &Wb[(size_t)(n0 + r0) * DIM + kq0];
  const short* gB1 = &Wb[(size_t)(n0 + r1) * DIM + kq0];
  short* lA0 = &As[wave * 512];
  short* lA1 = &As[wave * 512 + 2048];
  short* lB0 = &Bs[wave * 512];
  short* lB1 = &Bs[wave * 512 + 2048];

  #pragma unroll 1
  for (int k0 = 0; k0 < DIM; k0 += 32) {
    __syncthreads();
    GLD16(gA0 + k0, lA0);
    GLD16(gA1 + k0, lA1);
    GLD16(gB0 + k0, lB0);
    GLD16(gB1 + k0, lB1);
    __syncthreads();

    short8 af[4], bf[4];
    #pragma unroll
    for (int ms = 0; ms < 4; ++ms)
      af[ms] = *(const short8*)&As[(wr + ms*16 + qm) * 32 + quad * 8];
    #pragma unroll
    for (int ns = 0; ns < 4; ++ns)
      bf[ns] = *(const short8*)&Bs[(wc + ns*16 + qm) * 32 + quad * 8];
    #pragma unroll
    for (int ms = 0; ms < 4; ++ms)
      #pragma unroll
      for (int ns = 0; ns < 4; ++ns)
        acc[ms][ns] = __builtin_amdgcn_mfma_f32_16x16x32_bf16(af[ms], bf[ns], acc[ms][ns], 0, 0, 0);
  }

  #pragma unroll
  for (int ns = 0; ns < 4; ++ns) {
    const int col = n0 + wc + ns*16 + qm;
    const float bias = bb[col];
    #pragma unroll
    for (int ms = 0; ms < 4; ++ms)
      #pragma unroll
      for (int r = 0; r < 4; ++r) {
        const int row = m0 + wr + ms*16 + quad*4 + r;
        out[(size_t)row * DIM + col] = acc[ms][ns][r] + bias;
      }
  }
}

// ---------------------------------------------------------------------------
// Kernel 2 (r2 version): row rFFT along w as MFMA GEMM (bf16 in, fp32 out).
// ---------------------------------------------------------------------------
__global__ __launch_bounds__(256) void k_rfft_w_mfma(
    const short* __restrict__ Xb,
    float* __restrict__ Sr, float* __restrict__ Si)
{
  __shared__ short Lx[96 * 72];   // [c][w], row stride 72 shorts
  const int t = threadIdx.x;
  const int wave = t >> 6, lane = t & 63;
  const int qm = lane & 15, quad = lane >> 4;
  const int bh = blockIdx.x;
  const int c0 = blockIdx.y * 96;
  const size_t xbase = (size_t)bh * (WW*DIM);
  const size_t obase = (size_t)bh * (KH*DIM);

  // stage Xb -> LDS transposed [c][w] bf16
  #pragma unroll
  for (int it = 0; it < 3; ++it) {
    const int i = t + it * 256;         // 0..767
    const int hd = i & 31;              // w-pair
    const int c4 = i >> 5;              // 0..23
    const size_t g0 = xbase + (size_t)(2*hd) * DIM + c0 + c4 * 4;
    const short4v ra = *(const short4v*)&Xb[g0];
    const short4v rb = *(const short4v*)&Xb[g0 + DIM];
    #pragma unroll
    for (int e = 0; e < 4; ++e) {
      const int d = (c4*4 + e) * 36 + hd;
      ((unsigned*)Lx)[d] = (unsigned)(unsigned short)ra[e] |
                           ((unsigned)(unsigned short)rb[e] << 16);
    }
  }

  // twiddle A-frags: m=k (qm), k=w (quad*8+j+32kk); e^{-i}, hi/lo split
  short8 Trh[2], Trl[2], Tih[2], Til[2];
  const int krow = wave * 16 + qm;
  #pragma unroll
  for (int kk = 0; kk < 2; ++kk) {
    #pragma unroll
    for (int j = 0; j < 8; ++j) {
      const int w = quad * 8 + j + kk * 32;
      const int ph = (krow * w) & 63;
      float s, c;
      sincosf((float)ph * TWOPI_OVER_64, &s, &c);
      const float tr = c, ti = -s;
      const short trh = f2bs(tr);
      const short tih = f2bs(ti);
      Trh[kk][j] = trh;  Trl[kk][j] = f2bs(tr - bs2f(trh));
      Tih[kk][j] = tih;  Til[kk][j] = f2bs(ti - bs2f(tih));
    }
  }
  __syncthreads();

  if (wave < 3) {
    const floatx4 zero = {0.f, 0.f, 0.f, 0.f};
    #pragma unroll 1
    for (int ct = 0; ct < 6; ++ct) {
      floatx4 Cr = zero, Ci = zero;
      #pragma unroll
      for (int kk = 0; kk < 2; ++kk) {
        const int a = (ct*16 + qm) * 72 + kk*32 + quad*8;
        const short8 xv = *(const short8*)&Lx[a];
        Cr = __builtin_amdgcn_mfma_f32_16x16x32_bf16(Trh[kk], xv, Cr, 0,0,0);
        Cr = __builtin_amdgcn_mfma_f32_16x16x32_bf16(Trl[kk], xv, Cr, 0,0,0);
        Ci = __builtin_amdgcn_mfma_f32_16x16x32_bf16(Tih[kk], xv, Ci, 0,0,0);
        Ci = __builtin_amdgcn_mfma_f32_16x16x32_bf16(Til[kk], xv, Ci, 0,0,0);
      }
      #pragma unroll
      for (int r = 0; r < 4; ++r) {
        const int ko = wave*16 + quad*4 + r;
        if (ko < KH) {
          const size_t o = obase + (size_t)ko * DIM + c0 + ct*16 + qm;
          Sr[o] = Cr[r];
          Si[o] = Ci[r];
        }
      }
    }
  }
}

// ---------------------------------------------------------------------------
// Kernel P: transpose + convert mixing weights to bf16 B^T fragments.
// Slots: 0=W1R 1=W1I 2=W2R 3=W2IN(-W2I)   (W1IN synthesized by sign-flip)
// ---------------------------------------------------------------------------
__global__ __launch_bounds__(256) void k_prep_w(
    const float* __restrict__ w1, const float* __restrict__ w2,
    short* __restrict__ Wout)
{
  const int arr = blockIdx.y;           // 0..3
  const int i = blockIdx.x * 256 + threadIdx.x;
  const int nb = i / (BS*BS);
  const int rem = i % (BS*BS);
  const int n = rem / BS;
  const int d = rem % BS;
  const float* src = (arr < 2) ? w1 : w2;
  const int j = arr & 1;
  const float s = (arr == 3) ? -1.f : 1.f;
  const float v = s * src[((size_t)(j*NBLK + nb) * BS + d) * BS + n];
  Wout[(size_t)arr * WSZ + i] = f2bs(v);
}

// ---------------------------------------------------------------------------
// Kernel P2: composite layer-2 weights so i2 depends only on (r1,i1):
//   i2 = r1@(W2R.W2I) + i1@(W2R - W2I.W2I) + (b2i + b2r@W2I)
// Slots: 4=W2RI frag, 5=W2X frag; b2x float vector.
// ---------------------------------------------------------------------------
__global__ __launch_bounds__(256) void k_prep_w2(
    const float* __restrict__ w2, const float* __restrict__ b2,
    short* __restrict__ Wout, float* __restrict__ b2x)
{
  const int i = blockIdx.x * 256 + threadIdx.x;   // 0..4*192*192-1
  const int n = i % BS;
  const int d = (i / BS) % BS;                    // wave-uniform (192 = 3*64)
  const int nb = i / (BS*BS);
  const float* R = w2 + (size_t)nb * BS * BS;            // w2[0][nb][d][k]
  const float* I = w2 + ((size_t)NBLK + nb) * BS * BS;   // w2[1][nb][d][k]
  const float* br = b2 + nb * BS;
  float ri = 0.f, ii = 0.f, bx = 0.f;
  #pragma unroll 4
  for (int m = 0; m < BS; ++m) {
    const float win = I[m*BS + n];      // coalesced over n
    ri += R[d*BS + m] * win;            // scalar (wave-uniform)
    ii += I[d*BS + m] * win;
    bx += br[m] * win;
  }
  const size_t o = ((size_t)nb * BS + n) * BS + d;   // frag layout [nb][n][d]
  Wout[(size_t)4 * WSZ + o] = f2bs(ri);
  Wout[(size_t)5 * WSZ + o] = f2bs(R[d*BS + n] - ii);
  if (d == 0) b2x[nb * BS + n] = b2[(NBLK + nb) * BS + n] + bx;
}

// ---------------------------------------------------------------------------
// Kernel F: FUSED fft_h -> MLP -> ifft_h — EXACT round-1 structure (136 us
// measured): fp32 Sr/Si IO, padded-72 DFT layout, 4 waves, (256,2) bounds,
// VGPR ~112. All later variants (bf16 IO, swizzle, prefetch, 8-wave)
// measured 152-192 us; fmix is latency-bound so byte savings don't pay.
// ---------------------------------------------------------------------------
__global__ __launch_bounds__(256, 2) void k_fmix(
    float* __restrict__ Sr, float* __restrict__ Si,
    const short* __restrict__ WT,
    const float* __restrict__ b1, const float* __restrict__ b2,
    const float* __restrict__ b2x)
{
  __shared__ short U[2 * 192 * 72];          // 55,296 B union
  short* Ldr = U;
  short* Ldi = U + 192 * 72;
  short* Amr = U;
  short* Ami = U + 64 * LROW;

  const int t = threadIdx.x;
  const int wave = t >> 6, lane = t & 63;
  const int qm = lane & 15, quad = lane >> 4;
  const int bk = blockIdx.x;
  const int b = bk / KH, k = bk % KH;
  const int nb = blockIdx.y;
  const int c0 = nb * BS;
  const size_t hstride = (size_t)KH * DIM;
  const size_t base = ((size_t)b * HH * KH + k) * DIM;

  // ---- twiddles at scale 1 (serve both DFT directions): C=cos S=sin SN=-sin
  short8 Ch[2], Cl[2], Sh[2], Sl[2], SNh[2], SNl[2];
  const int hp = wave * 16 + qm;
  #pragma unroll
  for (int kk = 0; kk < 2; ++kk)
    #pragma unroll
    for (int j = 0; j < 8; ++j) {
      const int h = quad*8 + j + kk*32;
      const int ph = (hp * h) & 63;
      float s, c;
      sincosf((float)ph * TWOPI_OVER_64, &s, &c);
      const short ch = f2bs(c), sh = f2bs(s);
      Ch[kk][j] = ch;  Cl[kk][j] = f2bs(c - bs2f(ch));
      Sh[kk][j] = sh;  Sl[kk][j] = f2bs(s - bs2f(sh));
      SNh[kk][j] = (short)(sh ^ (short)0x8000);
      SNl[kk][j] = (short)(Sl[kk][j] ^ (short)0x8000);
    }

  // ---- phase 1: stage Sr/Si (64 h x 192 c) -> Ld [c][h] bf16
  #pragma unroll
  for (int it = 0; it < 6; ++it) {
    const int i = t + it * 256;         // 0..1535
    const int hd = i & 31;              // h-pair
    const int c4 = i >> 5;              // 0..47
    const size_t g0 = base + (size_t)(2*hd) * hstride + c0 + c4 * 4;
    const float4 ra = *(const float4*)&Sr[g0];
    const float4 rb = *(const float4*)&Sr[g0 + hstride];
    const float4 ia = *(const float4*)&Si[g0];
    const float4 ib = *(const float4*)&Si[g0 + hstride];
    const float raf[4] = {ra.x, ra.y, ra.z, ra.w};
    const float rbf[4] = {rb.x, rb.y, rb.z, rb.w};
    const float iaf[4] = {ia.x, ia.y, ia.z, ia.w};
    const float ibf[4] = {ib.x, ib.y, ib.z, ib.w};
    #pragma unroll
    for (int e = 0; e < 4; ++e) {
      const int d = (c4*4 + e) * 36 + hd;
      ((unsigned*)Ldr)[d] = (unsigned)(unsigned short)f2bs(raf[e]) |
                            ((unsigned)(unsigned short)f2bs(rbf[e]) << 16);
      ((unsigned*)Ldi)[d] = (unsigned)(unsigned short)f2bs(iaf[e]) |
                            ((unsigned)(unsigned short)f2bs(ibf[e]) << 16);
    }
  }
  __syncthreads();

  // ---- phase 2: forward DFT along h (ti = -s): Fr=C.xr+S.xi, Fi=SN.xr+C.xi
  const floatx4 zero = {0.f, 0.f, 0.f, 0.f};
  floatx4 Fr[12], Fi[12];
  #pragma unroll
  for (int ct = 0; ct < 12; ++ct) { Fr[ct] = zero; Fi[ct] = zero; }
  #pragma unroll
  for (int ct = 0; ct < 12; ++ct)
    #pragma unroll
    for (int kk = 0; kk < 2; ++kk) {
      const int a = (ct*16 + qm) * 72 + kk*32 + quad*8;
      const short8 sr = *(const short8*)&Ldr[a];
      const short8 si = *(const short8*)&Ldi[a];
      Fr[ct] = __builtin_amdgcn_mfma_f32_16x16x32_bf16(Ch[kk],  sr, Fr[ct], 0,0,0);
      Fr[ct] = __builtin_amdgcn_mfma_f32_16x16x32_bf16(Cl[kk],  sr, Fr[ct], 0,0,0);
      Fr[ct] = __builtin_amdgcn_mfma_f32_16x16x32_bf16(Sh[kk],  si, Fr[ct], 0,0,0);
      Fr[ct] = __builtin_amdgcn_mfma_f32_16x16x32_bf16(Sl[kk],  si, Fr[ct], 0,0,0);
      Fi[ct] = __builtin_amdgcn_mfma_f32_16x16x32_bf16(SNh[kk], sr, Fi[ct], 0,0,0);
      Fi[ct] = __builtin_amdgcn_mfma_f32_16x16x32_bf16(SNl[kk], sr, Fi[ct], 0,0,0);
      Fi[ct] = __builtin_amdgcn_mfma_f32_16x16x32_bf16(Ch[kk],  si, Fi[ct], 0,0,0);
      Fi[ct] = __builtin_amdgcn_mfma_f32_16x16x32_bf16(Cl[kk],  si, Fi[ct], 0,0,0);
    }
  __syncthreads();   // Ld dead; U becomes Am

  // ---- phase 3: write mix input = F * (1/64) (exact scale), bf16 -> Am
  #pragma unroll
  for (int ct = 0; ct < 12; ++ct)
    #pragma unroll
    for (int r = 0; r < 4; ++r) {
      const int row = wave*16 + quad*4 + r;    // h-point = mix row
      const int c = ct*16 + qm;
      Amr[row * LROW + c] = f2bs(Fr[ct][r] * 0.015625f);
      Ami[row * LROW + c] = f2bs(Fi[ct][r] * 0.015625f);
    }
  __syncthreads();

  // ---- mix setup
  const short* W1R  = WT;
  const short* W1I  = WT + 1 * (size_t)WSZ;
  const short* W2R  = WT + 2 * (size_t)WSZ;
  const short* W2IN = WT + 3 * (size_t)WSZ;
  const short* W2RI = WT + 4 * (size_t)WSZ;
  const short* W2X  = WT + 5 * (size_t)WSZ;

  int nl[3];
  size_t wb[3];
  #pragma unroll
  for (int nt = 0; nt < 3; ++nt) {
    nl[nt] = wave * 48 + nt * 16 + qm;
    wb[nt] = (size_t)(c0 + nl[nt]) * BS + quad * 8;
  }

  // ---- phase 4: layer 1 (r1 = relu(xr@W1R - xi@W1I + b1r), i1 = ...)
  floatx4 aR[4][3], aI[4][3];
  #pragma unroll
  for (int ms = 0; ms < 4; ++ms)
    #pragma unroll
    for (int nt = 0; nt < 3; ++nt) { aR[ms][nt] = zero; aI[ms][nt] = zero; }

  #pragma unroll 1
  for (int k0 = 0; k0 < BS; k0 += 32) {
    short8 xr[4], xi[4];
    #pragma unroll
    for (int ms = 0; ms < 4; ++ms) {
      const int a = (ms*16 + qm) * LROW + k0 + quad * 8;
      xr[ms] = *(const short8*)&Amr[a];
      xi[ms] = *(const short8*)&Ami[a];
    }
    #pragma unroll
    for (int nt = 0; nt < 3; ++nt) {
      const short8 br = *(const short8*)&W1R[wb[nt] + k0];
      const short8 bi = *(const short8*)&W1I[wb[nt] + k0];
      short8 bin;                                   // -W1I via sign-bit flip
      *(uint4v*)&bin = *(const uint4v*)&bi ^ 0x80008000u;
      #pragma unroll
      for (int ms = 0; ms < 4; ++ms) {
        aR[ms][nt] = __builtin_amdgcn_mfma_f32_16x16x32_bf16(xr[ms], br,  aR[ms][nt], 0,0,0);
        aR[ms][nt] = __builtin_amdgcn_mfma_f32_16x16x32_bf16(xi[ms], bin, aR[ms][nt], 0,0,0);
        aI[ms][nt] = __builtin_amdgcn_mfma_f32_16x16x32_bf16(xr[ms], bi,  aI[ms][nt], 0,0,0);
        aI[ms][nt] = __builtin_amdgcn_mfma_f32_16x16x32_bf16(xi[ms], br,  aI[ms][nt], 0,0,0);
      }
    }
  }
  __syncthreads();
  #pragma unroll
  for (int nt = 0; nt < 3; ++nt) {
    const float b1r = b1[nb * BS + nl[nt]];
    const float b1i = b1[(NBLK + nb) * BS + nl[nt]];
    #pragma unroll
    for (int ms = 0; ms < 4; ++ms)
      #pragma unroll
      for (int r = 0; r < 4; ++r) {
        const int row = ms*16 + quad*4 + r;
        Amr[row * LROW + nl[nt]] = f2bs(fmaxf(aR[ms][nt][r] + b1r, 0.f));
        Ami[row * LROW + nl[nt]] = f2bs(fmaxf(aI[ms][nt][r] + b1i, 0.f));
      }
  }
  __syncthreads();

  // ---- phase 5: layer 2 merged: r2 = r1@W2R + i1@W2IN; i2 = r1@W2RI + i1@W2X
  floatx4 c2r[4][3], c2i[4][3];
  #pragma unroll
  for (int ms = 0; ms < 4; ++ms)
    #pragma unroll
    for (int nt = 0; nt < 3; ++nt) { c2r[ms][nt] = zero; c2i[ms][nt] = zero; }

  #pragma unroll 1
  for (int k0 = 0; k0 < BS; k0 += 32) {
    short8 r1[4], i1[4];
    #pragma unroll
    for (int ms = 0; ms < 4; ++ms) {
      const int a = (ms*16 + qm) * LROW + k0 + quad * 8;
      r1[ms] = *(const short8*)&Amr[a];
      i1[ms] = *(const short8*)&Ami[a];
    }
    #pragma unroll
    for (int nt = 0; nt < 3; ++nt) {
      const short8 w_r  = *(const short8*)&W2R [wb[nt] + k0];
      const short8 w_in = *(const short8*)&W2IN[wb[nt] + k0];
      const short8 w_ri = *(const short8*)&W2RI[wb[nt] + k0];
      const short8 w_x  = *(const short8*)&W2X [wb[nt] + k0];
      #pragma unroll
      for (int ms = 0; ms < 4; ++ms) {
        c2r[ms][nt] = __builtin_amdgcn_mfma_f32_16x16x32_bf16(r1[ms], w_r,  c2r[ms][nt], 0,0,0);
        c2r[ms][nt] = __builtin_amdgcn_mfma_f32_16x16x32_bf16(i1[ms], w_in, c2r[ms][nt], 0,0,0);
        c2i[ms][nt] = __builtin_amdgcn_mfma_f32_16x16x32_bf16(r1[ms], w_ri, c2i[ms][nt], 0,0,0);
        c2i[ms][nt] = __builtin_amdgcn_mfma_f32_16x16x32_bf16(i1[ms], w_x,  c2i[ms][nt], 0,0,0);
      }
    }
  }
  __syncthreads();   // Am dead; U becomes Ld again

  // ---- phase 6: stage r2+b2r, i2+b2x -> Ld [c][h] bf16 for inverse DFT
  #pragma unroll
  for (int nt = 0; nt < 3; ++nt) {
    const float b2r = b2 [nb * BS + nl[nt]];
    const float bxi = b2x[nb * BS + nl[nt]];
    #pragma unroll
    for (int ms = 0; ms < 4; ++ms)
      #pragma unroll
      for (int r = 0; r < 4; ++r) {
        const int row = ms*16 + quad*4 + r;    // h
        const int c = nl[nt];
        Ldr[c * 72 + row] = f2bs(c2r[ms][nt][r] + b2r);
        Ldi[c * 72 + row] = f2bs(c2i[ms][nt][r] + bxi);
      }
  }
  __syncthreads();

  // ---- phase 7: inverse DFT (ti = +s): Cr=C.gr+SN.gi, Ci=S.gr+C.gi -> global
  #pragma unroll 1
  for (int ct = 0; ct < 12; ++ct) {
    floatx4 Cr = zero, Ci = zero;
    #pragma unroll
    for (int kk = 0; kk < 2; ++kk) {
      const int a = (ct*16 + qm) * 72 + kk*32 + quad*8;
      const short8 gr = *(const short8*)&Ldr[a];
      const short8 gi = *(const short8*)&Ldi[a];
      Cr = __builtin_amdgcn_mfma_f32_16x16x32_bf16(Ch[kk],  gr, Cr, 0,0,0);
      Cr = __builtin_amdgcn_mfma_f32_16x16x32_bf16(Cl[kk],  gr, Cr, 0,0,0);
      Cr = __builtin_amdgcn_mfma_f32_16x16x32_bf16(SNh[kk], gi, Cr, 0,0,0);
      Cr = __builtin_amdgcn_mfma_f32_16x16x32_bf16(SNl[kk], gi, Cr, 0,0,0);
      Ci = __builtin_amdgcn_mfma_f32_16x16x32_bf16(Sh[kk],  gr, Ci, 0,0,0);
      Ci = __builtin_amdgcn_mfma_f32_16x16x32_bf16(Sl[kk],  gr, Ci, 0,0,0);
      Ci = __builtin_amdgcn_mfma_f32_16x16x32_bf16(Ch[kk],  gi, Ci, 0,0,0);
      Ci = __builtin_amdgcn_mfma_f32_16x16x32_bf16(Cl[kk],  gi, Ci, 0,0,0);
    }
    #pragma unroll
    for (int r = 0; r < 4; ++r) {
      const int hpo = wave*16 + quad*4 + r;
      const size_t o = base + (size_t)hpo * hstride + c0 + ct*16 + qm;
      Sr[o] = Cr[r];
      Si[o] = Ci[r];
    }
  }
}

// ---------------------------------------------------------------------------
// Kernel 6 (r2 version): c2r inverse along k + bias partial add (fp32 RMW).
// ---------------------------------------------------------------------------
__global__ __launch_bounds__(256) void k_irfft_w_mfma(
    const float* __restrict__ Sr, const float* __restrict__ Si,
    float* __restrict__ out)
{
  __shared__ short Lr[96 * 72];   // [c][k], zero-padded k>=33
  __shared__ short Li[96 * 72];
  const int t = threadIdx.x;
  const int wave = t >> 6, lane = t & 63;
  const int qm = lane & 15, quad = lane >> 4;
  const int bh = blockIdx.x;
  const int c0 = blockIdx.y * 96;
  const size_t gbase = (size_t)bh * (KH*DIM);
  const size_t obase = (size_t)bh * (WW*DIM);

  #pragma unroll
  for (int it = 0; it < 3; ++it) {
    const int i = t + it * 256;
    const int hd = i & 31;              // k-pair: 2hd, 2hd+1
    const int c4 = i >> 5;
    const int ka = 2*hd, kb = 2*hd + 1;
    float4 ra = {0.f,0.f,0.f,0.f}, rb = ra, ia = ra, ib = ra;
    if (ka < KH) {
      const size_t g0 = gbase + (size_t)ka * DIM + c0 + c4 * 4;
      ra = *(const float4*)&Sr[g0];
      ia = *(const float4*)&Si[g0];
    }
    if (kb < KH) {
      const size_t g1 = gbase + (size_t)kb * DIM + c0 + c4 * 4;
      rb = *(const float4*)&Sr[g1];
      ib = *(const float4*)&Si[g1];
    }
    const float raf[4] = {ra.x, ra.y, ra.z, ra.w};
    const float rbf[4] = {rb.x, rb.y, rb.z, rb.w};
    const float iaf[4] = {ia.x, ia.y, ia.z, ia.w};
    const float ibf[4] = {ib.x, ib.y, ib.z, ib.w};
    #pragma unroll
    for (int e = 0; e < 4; ++e) {
      const int d = (c4*4 + e) * 36 + hd;
      ((unsigned*)Lr)[d] = (unsigned)(unsigned short)f2bs(raf[e]) |
                           ((unsigned)(unsigned short)f2bs(rbf[e]) << 16);
      ((unsigned*)Li)[d] = (unsigned)(unsigned short)f2bs(iaf[e]) |
                           ((unsigned)(unsigned short)f2bs(ibf[e]) << 16);
    }
  }

  short8 Arh[2], Arl[2], Aih[2], Ail[2];
  const int wrow = wave * 16 + qm;
  #pragma unroll
  for (int kk = 0; kk < 2; ++kk) {
    #pragma unroll
    for (int j = 0; j < 8; ++j) {
      const int k = quad * 8 + j + kk * 32;
      float ar = 0.f, ai = 0.f;
      if (k < KH) {
        const int ph = (wrow * k) & 63;
        float s, c;
        sincosf((float)ph * TWOPI_OVER_64, &s, &c);
        const float ck = (k == 0 || k == 32) ? (1.0f/64.0f) : (2.0f/64.0f);
        ar = ck * c;
        ai = -ck * s;
      }
      const short arh = f2bs(ar);
      const short aih = f2bs(ai);
      Arh[kk][j] = arh;  Arl[kk][j] = f2bs(ar - bs2f(arh));
      Aih[kk][j] = aih;  Ail[kk][j] = f2bs(ai - bs2f(aih));
    }
  }
  __syncthreads();

  const floatx4 zero = {0.f, 0.f, 0.f, 0.f};
  #pragma unroll 1
  for (int ct = 0; ct < 6; ++ct) {
    floatx4 C = zero;
    #pragma unroll
    for (int kk = 0; kk < 2; ++kk) {
      const int a = (ct*16 + qm) * 72 + kk*32 + quad*8;
      const short8 gr = *(const short8*)&Lr[a];
      const short8 gi = *(const short8*)&Li[a];
      C = __builtin_amdgcn_mfma_f32_16x16x32_bf16(Arh[kk], gr, C, 0,0,0);
      C = __builtin_amdgcn_mfma_f32_16x16x32_bf16(Arl[kk], gr, C, 0,0,0);
      C = __builtin_amdgcn_mfma_f32_16x16x32_bf16(Aih[kk], gi, C, 0,0,0);
      C = __builtin_amdgcn_mfma_f32_16x16x32_bf16(Ail[kk], gi, C, 0,0,0);
    }
    #pragma unroll
    for (int r = 0; r < 4; ++r) {
      const int w = wave*16 + quad*4 + r;
      const size_t o = obase + (size_t)w * DIM + c0 + ct*16 + qm;
      out[o] += C[r];    // add bias partial from k_bias_gemm3
    }
  }
}

// ---------------------------------------------------------------------------
extern "C" void kernel_launch(void* const* d_in, const int* in_sizes, int n_in,
                              void* d_out, int out_size, void* d_ws, size_t ws_size,
                              hipStream_t stream) {
  const float* x  = (const float*)d_in[0];
  const float* w1 = (const float*)d_in[1];
  const float* b1 = (const float*)d_in[2];
  const float* w2 = (const float*)d_in[3];
  const float* b2 = (const float*)d_in[4];
  const float* bw = (const float*)d_in[5];
  const float* bb = (const float*)d_in[6];
  float* out = (float*)d_out;

  float* Sr = (float*)d_ws;
  float* Si = Sr + (size_t)NPTS * DIM;
  short* WT = (short*)(Si + (size_t)NPTS * DIM);
  short* Xb = WT + (size_t)6 * WSZ;
  short* Wb = Xb + (size_t)BATCH * HH * WW * DIM;
  float* b2x = (float*)(Wb + (size_t)DIM * DIM);

  // C) convert X and bias_w to bf16
  k_convx<<<2048, 256, 0, stream>>>(x, Xb);
  k_convw<<<(DIM*DIM/4)/256, 256, 0, stream>>>(bw, Wb);
  // P) transpose+convert mixing weights to bf16 fragments (4 arrays)
  k_prep_w<<<dim3(WSZ/256, 4), 256, 0, stream>>>(w1, w2, WT);
  // P2) composite layer-2 weights + bias for merged real/imag phase
  k_prep_w2<<<dim3(WSZ/256), 256, 0, stream>>>(w2, b2, WT, b2x);
  // 1) bias = x @ bias_w^T + bias_b  -> d_out (fp32 partial)
  k_bias_gemm3<<<dim3(32768/128, DIM/128), 256, 0, stream>>>(Xb, Wb, bb, out);
  // 2) forward rfft along w via MFMA (unnormalized), fp32 out
  k_rfft_w_mfma<<<dim3(BATCH*HH, DIM/96), 256, 0, stream>>>(Xb, Sr, Si);
  // 3-5) FUSED: fft_h -> block MLP -> ifft_h (round-1 proven config)
  k_fmix<<<dim3(BATCH*KH, NBLK), 256, 0, stream>>>(Sr, Si, WT, b1, b2, b2x);
  // 6) c2r inverse along k via MFMA + bias partial -> final fp32 output
  k_irfft_w_mfma<<<dim3(BATCH*HH, DIM/96), 256, 0, stream>>>(Sr, Si, out);
}

// Round 7
// 464.195 us; speedup vs baseline: 1.1280x; 1.0420x over previous
//
#include <hip/hip_runtime.h>

#define DIM 768
#define NBLK 4
#define BS 192
#define BATCH 8
#define HH 64
#define WW 64
#define KH 33                  // W/2+1 bins
#define NPTS (BATCH*HH*KH)     // 16896 frequency points
#define TWOPI_OVER_64 0.0981747704246810387f
#define LROW 200               // mix LDS row stride in bf16
#define WSZ (NBLK*BS*BS)

typedef __attribute__((ext_vector_type(8))) short short8;
typedef __attribute__((ext_vector_type(4))) short short4v;
typedef __attribute__((ext_vector_type(4))) float floatx4;
typedef __attribute__((ext_vector_type(4))) unsigned int uint4v;

static __device__ __forceinline__ short f2bs(float f) {
  union { float f; unsigned int i; } v; v.f = f;
  unsigned int x = v.i;
  return (short)((x + 0x7fffu + ((x >> 16) & 1u)) >> 16);
}
static __device__ __forceinline__ float bs2f(short s) {
  union { unsigned int i; float f; } v; v.i = ((unsigned int)(unsigned short)s) << 16; return v.f;
}

// async global->LDS, 16B per lane; lds dest must be wave-uniform base.
#define GLD16(gp, lp) \
  __builtin_amdgcn_global_load_lds( \
      (const __attribute__((address_space(1))) unsigned int*)(gp), \
      (__attribute__((address_space(3))) unsigned int*)(lp), 16, 0, 0)

// ---------------------------------------------------------------------------
// Kernel C: convert X (fp32) -> Xb (bf16), RNE.
// ---------------------------------------------------------------------------
__global__ __launch_bounds__(256) void k_convx(
    const float* __restrict__ X, short* __restrict__ Xb)
{
  const int i = blockIdx.x * 256 + threadIdx.x;
  const float4* X4 = (const float4*)X;
  #pragma unroll
  for (int it = 0; it < 12; ++it) {
    const int idx = i + it * (2048 * 256);
    const float4 v = X4[idx];
    short4v p = { f2bs(v.x), f2bs(v.y), f2bs(v.z), f2bs(v.w) };
    *(short4v*)&Xb[(size_t)idx * 4] = p;
  }
}

// convert bias_w (768x768 fp32) -> bf16
__global__ __launch_bounds__(256) void k_convw(
    const float* __restrict__ W, short* __restrict__ Wb)
{
  const int idx = blockIdx.x * 256 + threadIdx.x;   // 147456 quads
  const float4 v = ((const float4*)W)[idx];
  short4v p = { f2bs(v.x), f2bs(v.y), f2bs(v.z), f2bs(v.w) };
  *(short4v*)&Wb[(size_t)idx * 4] = p;
}

// ---------------------------------------------------------------------------
// Kernel 1: bias GEMM via global_load_lds on bf16.
// Bias[m,n] = bf16( sum_k Xb[m,k]*Wb[n,k] + bb[n] )   (final add in k_irfft)
// ---------------------------------------------------------------------------
__global__ __launch_bounds__(256) void k_bias_gemm3(
    const short* __restrict__ Xb, const short* __restrict__ Wb,
    const float* __restrict__ bb, short* __restrict__ Bias)
{
  __shared__ short As[128 * 32];   // [row][k] rows of 64B
  __shared__ short Bs[128 * 32];
  const int t = threadIdx.x;
  const int wave = t >> 6, lane = t & 63;
  const int qm = lane & 15, quad = lane >> 4;
  const int wr = (wave >> 1) * 64;
  const int wc = (wave & 1) * 64;
  const int m0 = blockIdx.x * 128, n0 = blockIdx.y * 128;

  floatx4 acc[4][4];
  const floatx4 zero = {0.f, 0.f, 0.f, 0.f};
  #pragma unroll
  for (int ms = 0; ms < 4; ++ms)
    #pragma unroll
    for (int ns = 0; ns < 4; ++ns) acc[ms][ns] = zero;

  const int r0 = t >> 2,        kq0 = (t & 3) * 8;
  const int r1 = (t + 256) >> 2;
  const short* gA0 = &Xb[(size_t)(m0 + r0) * DIM + kq0];
  const short* gA1 = &Xb[(size_t)(m0 + r1) * DIM + kq0];
  const short* gB0 = &Wb[(size_t)(n0 + r0) * DIM + kq0];
  const short* gB1 = &Wb[(size_t)(n0 + r1) * DIM + kq0];
  short* lA0 = &As[wave * 512];
  short* lA1 = &As[wave * 512 + 2048];
  short* lB0 = &Bs[wave * 512];
  short* lB1 = &Bs[wave * 512 + 2048];

  #pragma unroll 1
  for (int k0 = 0; k0 < DIM; k0 += 32) {
    __syncthreads();
    GLD16(gA0 + k0, lA0);
    GLD16(gA1 + k0, lA1);
    GLD16(gB0 + k0, lB0);
    GLD16(gB1 + k0, lB1);
    __syncthreads();

    short8 af[4], bf[4];
    #pragma unroll
    for (int ms = 0; ms < 4; ++ms)
      af[ms] = *(const short8*)&As[(wr + ms*16 + qm) * 32 + quad * 8];
    #pragma unroll
    for (int ns = 0; ns < 4; ++ns)
      bf[ns] = *(const short8*)&Bs[(wc + ns*16 + qm) * 32 + quad * 8];
    #pragma unroll
    for (int ms = 0; ms < 4; ++ms)
      #pragma unroll
      for (int ns = 0; ns < 4; ++ns)
        acc[ms][ns] = __builtin_amdgcn_mfma_f32_16x16x32_bf16(af[ms], bf[ns], acc[ms][ns], 0, 0, 0);
  }

  #pragma unroll
  for (int ns = 0; ns < 4; ++ns) {
    const int col = n0 + wc + ns*16 + qm;
    const float bias = bb[col];
    #pragma unroll
    for (int ms = 0; ms < 4; ++ms)
      #pragma unroll
      for (int r = 0; r < 4; ++r) {
        const int row = m0 + wr + ms*16 + quad*4 + r;
        Bias[(size_t)row * DIM + col] = f2bs(acc[ms][ns][r] + bias);
      }
  }
}

// ---------------------------------------------------------------------------
// Kernel 2: row rFFT along w as MFMA GEMM (bf16 in, bf16 out).
// ---------------------------------------------------------------------------
__global__ __launch_bounds__(256) void k_rfft_w_mfma(
    const short* __restrict__ Xb,
    short* __restrict__ Sr, short* __restrict__ Si)
{
  __shared__ short Lx[96 * 72];   // [c][w], row stride 72 shorts
  const int t = threadIdx.x;
  const int wave = t >> 6, lane = t & 63;
  const int qm = lane & 15, quad = lane >> 4;
  const int bh = blockIdx.x;
  const int c0 = blockIdx.y * 96;
  const size_t xbase = (size_t)bh * (WW*DIM);
  const size_t obase = (size_t)bh * (KH*DIM);

  // stage Xb -> LDS transposed [c][w] bf16
  #pragma unroll
  for (int it = 0; it < 3; ++it) {
    const int i = t + it * 256;         // 0..767
    const int hd = i & 31;              // w-pair
    const int c4 = i >> 5;              // 0..23
    const size_t g0 = xbase + (size_t)(2*hd) * DIM + c0 + c4 * 4;
    const short4v ra = *(const short4v*)&Xb[g0];
    const short4v rb = *(const short4v*)&Xb[g0 + DIM];
    #pragma unroll
    for (int e = 0; e < 4; ++e) {
      const int d = (c4*4 + e) * 36 + hd;
      ((unsigned*)Lx)[d] = (unsigned)(unsigned short)ra[e] |
                           ((unsigned)(unsigned short)rb[e] << 16);
    }
  }

  // twiddle A-frags: m=k (qm), k=w (quad*8+j+32kk); e^{-i}, hi/lo split
  short8 Trh[2], Trl[2], Tih[2], Til[2];
  const int krow = wave * 16 + qm;
  #pragma unroll
  for (int kk = 0; kk < 2; ++kk) {
    #pragma unroll
    for (int j = 0; j < 8; ++j) {
      const int w = quad * 8 + j + kk * 32;
      const int ph = (krow * w) & 63;
      float s, c;
      sincosf((float)ph * TWOPI_OVER_64, &s, &c);
      const float tr = c, ti = -s;
      const short trh = f2bs(tr);
      const short tih = f2bs(ti);
      Trh[kk][j] = trh;  Trl[kk][j] = f2bs(tr - bs2f(trh));
      Tih[kk][j] = tih;  Til[kk][j] = f2bs(ti - bs2f(tih));
    }
  }
  __syncthreads();

  if (wave < 3) {
    const floatx4 zero = {0.f, 0.f, 0.f, 0.f};
    #pragma unroll 1
    for (int ct = 0; ct < 6; ++ct) {
      floatx4 Cr = zero, Ci = zero;
      #pragma unroll
      for (int kk = 0; kk < 2; ++kk) {
        const int a = (ct*16 + qm) * 72 + kk*32 + quad*8;
        const short8 xv = *(const short8*)&Lx[a];
        Cr = __builtin_amdgcn_mfma_f32_16x16x32_bf16(Trh[kk], xv, Cr, 0,0,0);
        Cr = __builtin_amdgcn_mfma_f32_16x16x32_bf16(Trl[kk], xv, Cr, 0,0,0);
        Ci = __builtin_amdgcn_mfma_f32_16x16x32_bf16(Tih[kk], xv, Ci, 0,0,0);
        Ci = __builtin_amdgcn_mfma_f32_16x16x32_bf16(Til[kk], xv, Ci, 0,0,0);
      }
      #pragma unroll
      for (int r = 0; r < 4; ++r) {
        const int ko = wave*16 + quad*4 + r;
        if (ko < KH) {
          const size_t o = obase + (size_t)ko * DIM + c0 + ct*16 + qm;
          Sr[o] = f2bs(Cr[r]);
          Si[o] = f2bs(Ci[r]);
        }
      }
    }
  }
}

// ---------------------------------------------------------------------------
// Kernel P: transpose + convert mixing weights to bf16 B^T fragments.
// Slots: 0=W1R 1=W1I 2=W2R 3=W2IN(-W2I)   (W1IN synthesized by sign-flip)
// ---------------------------------------------------------------------------
__global__ __launch_bounds__(256) void k_prep_w(
    const float* __restrict__ w1, const float* __restrict__ w2,
    short* __restrict__ Wout)
{
  const int arr = blockIdx.y;           // 0..3
  const int i = blockIdx.x * 256 + threadIdx.x;
  const int nb = i / (BS*BS);
  const int rem = i % (BS*BS);
  const int n = rem / BS;
  const int d = rem % BS;
  const float* src = (arr < 2) ? w1 : w2;
  const int j = arr & 1;
  const float s = (arr == 3) ? -1.f : 1.f;
  const float v = s * src[((size_t)(j*NBLK + nb) * BS + d) * BS + n];
  Wout[(size_t)arr * WSZ + i] = f2bs(v);
}

// ---------------------------------------------------------------------------
// Kernel P2: composite layer-2 weights so i2 depends only on (r1,i1):
//   i2 = r1@(W2R.W2I) + i1@(W2R - W2I.W2I) + (b2i + b2r@W2I)
// Slots: 4=W2RI frag, 5=W2X frag; b2x float vector.
// ---------------------------------------------------------------------------
__global__ __launch_bounds__(256) void k_prep_w2(
    const float* __restrict__ w2, const float* __restrict__ b2,
    short* __restrict__ Wout, float* __restrict__ b2x)
{
  const int i = blockIdx.x * 256 + threadIdx.x;   // 0..4*192*192-1
  const int n = i % BS;
  const int d = (i / BS) % BS;                    // wave-uniform (192 = 3*64)
  const int nb = i / (BS*BS);
  const float* R = w2 + (size_t)nb * BS * BS;            // w2[0][nb][d][k]
  const float* I = w2 + ((size_t)NBLK + nb) * BS * BS;   // w2[1][nb][d][k]
  const float* br = b2 + nb * BS;
  float ri = 0.f, ii = 0.f, bx = 0.f;
  #pragma unroll 4
  for (int m = 0; m < BS; ++m) {
    const float win = I[m*BS + n];      // coalesced over n
    ri += R[d*BS + m] * win;            // scalar (wave-uniform)
    ii += I[d*BS + m] * win;
    bx += br[m] * win;
  }
  const size_t o = ((size_t)nb * BS + n) * BS + d;   // frag layout [nb][n][d]
  Wout[(size_t)4 * WSZ + o] = f2bs(ri);
  Wout[(size_t)5 * WSZ + o] = f2bs(R[d*BS + n] - ii);
  if (d == 0) b2x[nb * BS + n] = b2[(NBLK + nb) * BS + n] + bx;
}

// ---------------------------------------------------------------------------
// Kernel F (v6): r6's EXACT proven structure (padded-72 LDS, 4 waves,
// (256,2), VGPR~112, 132 us) with ONLY the global IO switched to bf16.
// Phase-1 staging becomes pure bit-pack (cheaper than r6's 48 f2bs);
// phase 7 adds 48 f2bs. This isolates bf16-IO from the confounds of
// r2 (VGPR squeeze), r3 (swizzled layout), r4 (reg-held staging+prefetch).
// ---------------------------------------------------------------------------
__global__ __launch_bounds__(256, 2) void k_fmix(
    short* __restrict__ Sr, short* __restrict__ Si,
    const short* __restrict__ WT,
    const float* __restrict__ b1, const float* __restrict__ b2,
    const float* __restrict__ b2x)
{
  __shared__ short U[2 * 192 * 72];          // 55,296 B union
  short* Ldr = U;
  short* Ldi = U + 192 * 72;
  short* Amr = U;
  short* Ami = U + 64 * LROW;

  const int t = threadIdx.x;
  const int wave = t >> 6, lane = t & 63;
  const int qm = lane & 15, quad = lane >> 4;
  const int bk = blockIdx.x;
  const int b = bk / KH, k = bk % KH;
  const int nb = blockIdx.y;
  const int c0 = nb * BS;
  const size_t hstride = (size_t)KH * DIM;
  const size_t base = ((size_t)b * HH * KH + k) * DIM;

  // ---- twiddles at scale 1 (serve both DFT directions): C=cos S=sin SN=-sin
  short8 Ch[2], Cl[2], Sh[2], Sl[2], SNh[2], SNl[2];
  const int hp = wave * 16 + qm;
  #pragma unroll
  for (int kk = 0; kk < 2; ++kk)
    #pragma unroll
    for (int j = 0; j < 8; ++j) {
      const int h = quad*8 + j + kk*32;
      const int ph = (hp * h) & 63;
      float s, c;
      sincosf((float)ph * TWOPI_OVER_64, &s, &c);
      const short ch = f2bs(c), sh = f2bs(s);
      Ch[kk][j] = ch;  Cl[kk][j] = f2bs(c - bs2f(ch));
      Sh[kk][j] = sh;  Sl[kk][j] = f2bs(s - bs2f(sh));
      SNh[kk][j] = (short)(sh ^ (short)0x8000);
      SNl[kk][j] = (short)(Sl[kk][j] ^ (short)0x8000);
    }

  // ---- phase 1: stage Sr/Si (bf16, 64 h x 192 c) -> Ld [c][h] bf16
  #pragma unroll
  for (int it = 0; it < 6; ++it) {
    const int i = t + it * 256;         // 0..1535
    const int hd = i & 31;              // h-pair
    const int c4 = i >> 5;              // 0..47
    const size_t g0 = base + (size_t)(2*hd) * hstride + c0 + c4 * 4;
    const short4v ra = *(const short4v*)&Sr[g0];
    const short4v rb = *(const short4v*)&Sr[g0 + hstride];
    const short4v ia = *(const short4v*)&Si[g0];
    const short4v ib = *(const short4v*)&Si[g0 + hstride];
    #pragma unroll
    for (int e = 0; e < 4; ++e) {
      const int d = (c4*4 + e) * 36 + hd;
      ((unsigned*)Ldr)[d] = (unsigned)(unsigned short)ra[e] |
                            ((unsigned)(unsigned short)rb[e] << 16);
      ((unsigned*)Ldi)[d] = (unsigned)(unsigned short)ia[e] |
                            ((unsigned)(unsigned short)ib[e] << 16);
    }
  }
  __syncthreads();

  // ---- phase 2: forward DFT along h (ti = -s): Fr=C.xr+S.xi, Fi=SN.xr+C.xi
  const floatx4 zero = {0.f, 0.f, 0.f, 0.f};
  floatx4 Fr[12], Fi[12];
  #pragma unroll
  for (int ct = 0; ct < 12; ++ct) { Fr[ct] = zero; Fi[ct] = zero; }
  #pragma unroll
  for (int ct = 0; ct < 12; ++ct)
    #pragma unroll
    for (int kk = 0; kk < 2; ++kk) {
      const int a = (ct*16 + qm) * 72 + kk*32 + quad*8;
      const short8 sr = *(const short8*)&Ldr[a];
      const short8 si = *(const short8*)&Ldi[a];
      Fr[ct] = __builtin_amdgcn_mfma_f32_16x16x32_bf16(Ch[kk],  sr, Fr[ct], 0,0,0);
      Fr[ct] = __builtin_amdgcn_mfma_f32_16x16x32_bf16(Cl[kk],  sr, Fr[ct], 0,0,0);
      Fr[ct] = __builtin_amdgcn_mfma_f32_16x16x32_bf16(Sh[kk],  si, Fr[ct], 0,0,0);
      Fr[ct] = __builtin_amdgcn_mfma_f32_16x16x32_bf16(Sl[kk],  si, Fr[ct], 0,0,0);
      Fi[ct] = __builtin_amdgcn_mfma_f32_16x16x32_bf16(SNh[kk], sr, Fi[ct], 0,0,0);
      Fi[ct] = __builtin_amdgcn_mfma_f32_16x16x32_bf16(SNl[kk], sr, Fi[ct], 0,0,0);
      Fi[ct] = __builtin_amdgcn_mfma_f32_16x16x32_bf16(Ch[kk],  si, Fi[ct], 0,0,0);
      Fi[ct] = __builtin_amdgcn_mfma_f32_16x16x32_bf16(Cl[kk],  si, Fi[ct], 0,0,0);
    }
  __syncthreads();   // Ld dead; U becomes Am

  // ---- phase 3: write mix input = F * (1/64) (exact scale), bf16 -> Am
  #pragma unroll
  for (int ct = 0; ct < 12; ++ct)
    #pragma unroll
    for (int r = 0; r < 4; ++r) {
      const int row = wave*16 + quad*4 + r;    // h-point = mix row
      const int c = ct*16 + qm;
      Amr[row * LROW + c] = f2bs(Fr[ct][r] * 0.015625f);
      Ami[row * LROW + c] = f2bs(Fi[ct][r] * 0.015625f);
    }
  __syncthreads();

  // ---- mix setup
  const short* W1R  = WT;
  const short* W1I  = WT + 1 * (size_t)WSZ;
  const short* W2R  = WT + 2 * (size_t)WSZ;
  const short* W2IN = WT + 3 * (size_t)WSZ;
  const short* W2RI = WT + 4 * (size_t)WSZ;
  const short* W2X  = WT + 5 * (size_t)WSZ;

  int nl[3];
  size_t wb[3];
  #pragma unroll
  for (int nt = 0; nt < 3; ++nt) {
    nl[nt] = wave * 48 + nt * 16 + qm;
    wb[nt] = (size_t)(c0 + nl[nt]) * BS + quad * 8;
  }

  // ---- phase 4: layer 1 (r1 = relu(xr@W1R - xi@W1I + b1r), i1 = ...)
  floatx4 aR[4][3], aI[4][3];
  #pragma unroll
  for (int ms = 0; ms < 4; ++ms)
    #pragma unroll
    for (int nt = 0; nt < 3; ++nt) { aR[ms][nt] = zero; aI[ms][nt] = zero; }

  #pragma unroll 1
  for (int k0 = 0; k0 < BS; k0 += 32) {
    short8 xr[4], xi[4];
    #pragma unroll
    for (int ms = 0; ms < 4; ++ms) {
      const int a = (ms*16 + qm) * LROW + k0 + quad * 8;
      xr[ms] = *(const short8*)&Amr[a];
      xi[ms] = *(const short8*)&Ami[a];
    }
    #pragma unroll
    for (int nt = 0; nt < 3; ++nt) {
      const short8 br = *(const short8*)&W1R[wb[nt] + k0];
      const short8 bi = *(const short8*)&W1I[wb[nt] + k0];
      short8 bin;                                   // -W1I via sign-bit flip
      *(uint4v*)&bin = *(const uint4v*)&bi ^ 0x80008000u;
      #pragma unroll
      for (int ms = 0; ms < 4; ++ms) {
        aR[ms][nt] = __builtin_amdgcn_mfma_f32_16x16x32_bf16(xr[ms], br,  aR[ms][nt], 0,0,0);
        aR[ms][nt] = __builtin_amdgcn_mfma_f32_16x16x32_bf16(xi[ms], bin, aR[ms][nt], 0,0,0);
        aI[ms][nt] = __builtin_amdgcn_mfma_f32_16x16x32_bf16(xr[ms], bi,  aI[ms][nt], 0,0,0);
        aI[ms][nt] = __builtin_amdgcn_mfma_f32_16x16x32_bf16(xi[ms], br,  aI[ms][nt], 0,0,0);
      }
    }
  }
  __syncthreads();
  #pragma unroll
  for (int nt = 0; nt < 3; ++nt) {
    const float b1r = b1[nb * BS + nl[nt]];
    const float b1i = b1[(NBLK + nb) * BS + nl[nt]];
    #pragma unroll
    for (int ms = 0; ms < 4; ++ms)
      #pragma unroll
      for (int r = 0; r < 4; ++r) {
        const int row = ms*16 + quad*4 + r;
        Amr[row * LROW + nl[nt]] = f2bs(fmaxf(aR[ms][nt][r] + b1r, 0.f));
        Ami[row * LROW + nl[nt]] = f2bs(fmaxf(aI[ms][nt][r] + b1i, 0.f));
      }
  }
  __syncthreads();

  // ---- phase 5: layer 2 merged: r2 = r1@W2R + i1@W2IN; i2 = r1@W2RI + i1@W2X
  floatx4 c2r[4][3], c2i[4][3];
  #pragma unroll
  for (int ms = 0; ms < 4; ++ms)
    #pragma unroll
    for (int nt = 0; nt < 3; ++nt) { c2r[ms][nt] = zero; c2i[ms][nt] = zero; }

  #pragma unroll 1
  for (int k0 = 0; k0 < BS; k0 += 32) {
    short8 r1[4], i1[4];
    #pragma unroll
    for (int ms = 0; ms < 4; ++ms) {
      const int a = (ms*16 + qm) * LROW + k0 + quad * 8;
      r1[ms] = *(const short8*)&Amr[a];
      i1[ms] = *(const short8*)&Ami[a];
    }
    #pragma unroll
    for (int nt = 0; nt < 3; ++nt) {
      const short8 w_r  = *(const short8*)&W2R [wb[nt] + k0];
      const short8 w_in = *(const short8*)&W2IN[wb[nt] + k0];
      const short8 w_ri = *(const short8*)&W2RI[wb[nt] + k0];
      const short8 w_x  = *(const short8*)&W2X [wb[nt] + k0];
      #pragma unroll
      for (int ms = 0; ms < 4; ++ms) {
        c2r[ms][nt] = __builtin_amdgcn_mfma_f32_16x16x32_bf16(r1[ms], w_r,  c2r[ms][nt], 0,0,0);
        c2r[ms][nt] = __builtin_amdgcn_mfma_f32_16x16x32_bf16(i1[ms], w_in, c2r[ms][nt], 0,0,0);
        c2i[ms][nt] = __builtin_amdgcn_mfma_f32_16x16x32_bf16(r1[ms], w_ri, c2i[ms][nt], 0,0,0);
        c2i[ms][nt] = __builtin_amdgcn_mfma_f32_16x16x32_bf16(i1[ms], w_x,  c2i[ms][nt], 0,0,0);
      }
    }
  }
  __syncthreads();   // Am dead; U becomes Ld again

  // ---- phase 6: stage r2+b2r, i2+b2x -> Ld [c][h] bf16 for inverse DFT
  #pragma unroll
  for (int nt = 0; nt < 3; ++nt) {
    const float b2r = b2 [nb * BS + nl[nt]];
    const float bxi = b2x[nb * BS + nl[nt]];
    #pragma unroll
    for (int ms = 0; ms < 4; ++ms)
      #pragma unroll
      for (int r = 0; r < 4; ++r) {
        const int row = ms*16 + quad*4 + r;    // h
        const int c = nl[nt];
        Ldr[c * 72 + row] = f2bs(c2r[ms][nt][r] + b2r);
        Ldi[c * 72 + row] = f2bs(c2i[ms][nt][r] + bxi);
      }
  }
  __syncthreads();

  // ---- phase 7: inverse DFT (ti = +s): Cr=C.gr+SN.gi, Ci=S.gr+C.gi -> global
  #pragma unroll 1
  for (int ct = 0; ct < 12; ++ct) {
    floatx4 Cr = zero, Ci = zero;
    #pragma unroll
    for (int kk = 0; kk < 2; ++kk) {
      const int a = (ct*16 + qm) * 72 + kk*32 + quad*8;
      const short8 gr = *(const short8*)&Ldr[a];
      const short8 gi = *(const short8*)&Ldi[a];
      Cr = __builtin_amdgcn_mfma_f32_16x16x32_bf16(Ch[kk],  gr, Cr, 0,0,0);
      Cr = __builtin_amdgcn_mfma_f32_16x16x32_bf16(Cl[kk],  gr, Cr, 0,0,0);
      Cr = __builtin_amdgcn_mfma_f32_16x16x32_bf16(SNh[kk], gi, Cr, 0,0,0);
      Cr = __builtin_amdgcn_mfma_f32_16x16x32_bf16(SNl[kk], gi, Cr, 0,0,0);
      Ci = __builtin_amdgcn_mfma_f32_16x16x32_bf16(Sh[kk],  gr, Ci, 0,0,0);
      Ci = __builtin_amdgcn_mfma_f32_16x16x32_bf16(Sl[kk],  gr, Ci, 0,0,0);
      Ci = __builtin_amdgcn_mfma_f32_16x16x32_bf16(Ch[kk],  gi, Ci, 0,0,0);
      Ci = __builtin_amdgcn_mfma_f32_16x16x32_bf16(Cl[kk],  gi, Ci, 0,0,0);
    }
    #pragma unroll
    for (int r = 0; r < 4; ++r) {
      const int hpo = wave*16 + quad*4 + r;
      const size_t o = base + (size_t)hpo * hstride + c0 + ct*16 + qm;
      Sr[o] = f2bs(Cr[r]);
      Si[o] = f2bs(Ci[r]);
    }
  }
}

// ---------------------------------------------------------------------------
// Kernel 6: c2r inverse along k as MFMA GEMM + bias add (bf16 in, fp32 out).
// ---------------------------------------------------------------------------
__global__ __launch_bounds__(256) void k_irfft_w_mfma(
    const short* __restrict__ Sr, const short* __restrict__ Si,
    const short* __restrict__ Bias, float* __restrict__ out)
{
  __shared__ short Lr[96 * 72];   // [c][k], zero-padded k>=33
  __shared__ short Li[96 * 72];
  const int t = threadIdx.x;
  const int wave = t >> 6, lane = t & 63;
  const int qm = lane & 15, quad = lane >> 4;
  const int bh = blockIdx.x;
  const int c0 = blockIdx.y * 96;
  const size_t gbase = (size_t)bh * (KH*DIM);
  const size_t obase = (size_t)bh * (WW*DIM);

  #pragma unroll
  for (int it = 0; it < 3; ++it) {
    const int i = t + it * 256;
    const int hd = i & 31;              // k-pair: 2hd, 2hd+1
    const int c4 = i >> 5;
    const int ka = 2*hd, kb = 2*hd + 1;
    short4v ra = {0,0,0,0}, rb = ra, ia = ra, ib = ra;
    if (ka < KH) {
      const size_t g0 = gbase + (size_t)ka * DIM + c0 + c4 * 4;
      ra = *(const short4v*)&Sr[g0];
      ia = *(const short4v*)&Si[g0];
    }
    if (kb < KH) {
      const size_t g1 = gbase + (size_t)kb * DIM + c0 + c4 * 4;
      rb = *(const short4v*)&Sr[g1];
      ib = *(const short4v*)&Si[g1];
    }
    #pragma unroll
    for (int e = 0; e < 4; ++e) {
      const int d = (c4*4 + e) * 36 + hd;
      ((unsigned*)Lr)[d] = (unsigned)(unsigned short)ra[e] |
                           ((unsigned)(unsigned short)rb[e] << 16);
      ((unsigned*)Li)[d] = (unsigned)(unsigned short)ia[e] |
                           ((unsigned)(unsigned short)ib[e] << 16);
    }
  }

  short8 Arh[2], Arl[2], Aih[2], Ail[2];
  const int wrow = wave * 16 + qm;
  #pragma unroll
  for (int kk = 0; kk < 2; ++kk) {
    #pragma unroll
    for (int j = 0; j < 8; ++j) {
      const int k = quad * 8 + j + kk * 32;
      float ar = 0.f, ai = 0.f;
      if (k < KH) {
        const int ph = (wrow * k) & 63;
        float s, c;
        sincosf((float)ph * TWOPI_OVER_64, &s, &c);
        const float ck = (k == 0 || k == 32) ? (1.0f/64.0f) : (2.0f/64.0f);
        ar = ck * c;
        ai = -ck * s;
      }
      const short arh = f2bs(ar);
      const short aih = f2bs(ai);
      Arh[kk][j] = arh;  Arl[kk][j] = f2bs(ar - bs2f(arh));
      Aih[kk][j] = aih;  Ail[kk][j] = f2bs(ai - bs2f(aih));
    }
  }
  __syncthreads();

  const floatx4 zero = {0.f, 0.f, 0.f, 0.f};
  #pragma unroll 1
  for (int ct = 0; ct < 6; ++ct) {
    floatx4 C = zero;
    #pragma unroll
    for (int kk = 0; kk < 2; ++kk) {
      const int a = (ct*16 + qm) * 72 + kk*32 + quad*8;
      const short8 gr = *(const short8*)&Lr[a];
      const short8 gi = *(const short8*)&Li[a];
      C = __builtin_amdgcn_mfma_f32_16x16x32_bf16(Arh[kk], gr, C, 0,0,0);
      C = __builtin_amdgcn_mfma_f32_16x16x32_bf16(Arl[kk], gr, C, 0,0,0);
      C = __builtin_amdgcn_mfma_f32_16x16x32_bf16(Aih[kk], gi, C, 0,0,0);
      C = __builtin_amdgcn_mfma_f32_16x16x32_bf16(Ail[kk], gi, C, 0,0,0);
    }
    #pragma unroll
    for (int r = 0; r < 4; ++r) {
      const int w = wave*16 + quad*4 + r;
      const size_t o = obase + (size_t)w * DIM + c0 + ct*16 + qm;
      out[o] = C[r] + bs2f(Bias[o]);    // single fp32 store, no RMW
    }
  }
}

// ---------------------------------------------------------------------------
extern "C" void kernel_launch(void* const* d_in, const int* in_sizes, int n_in,
                              void* d_out, int out_size, void* d_ws, size_t ws_size,
                              hipStream_t stream) {
  const float* x  = (const float*)d_in[0];
  const float* w1 = (const float*)d_in[1];
  const float* b1 = (const float*)d_in[2];
  const float* w2 = (const float*)d_in[3];
  const float* b2 = (const float*)d_in[4];
  const float* bw = (const float*)d_in[5];
  const float* bb = (const float*)d_in[6];
  float* out = (float*)d_out;

  short* Sr = (short*)d_ws;
  short* Si = Sr + (size_t)NPTS * DIM;
  short* WT = Si + (size_t)NPTS * DIM;
  short* Xb = WT + (size_t)6 * WSZ;
  short* Wb = Xb + (size_t)BATCH * HH * WW * DIM;
  short* Bias = Wb + (size_t)DIM * DIM;
  float* b2x = (float*)(Bias + (size_t)BATCH * HH * WW * DIM);

  // C) convert X and bias_w to bf16
  k_convx<<<2048, 256, 0, stream>>>(x, Xb);
  k_convw<<<(DIM*DIM/4)/256, 256, 0, stream>>>(bw, Wb);
  // P) transpose+convert mixing weights to bf16 fragments (4 arrays)
  k_prep_w<<<dim3(WSZ/256, 4), 256, 0, stream>>>(w1, w2, WT);
  // P2) composite layer-2 weights + bias for merged real/imag phase
  k_prep_w2<<<dim3(WSZ/256), 256, 0, stream>>>(w2, b2, WT, b2x);
  // 1) bias partial = x @ bias_w^T + bias_b  -> bf16 buffer
  k_bias_gemm3<<<dim3(32768/128, DIM/128), 256, 0, stream>>>(Xb, Wb, bb, Bias);
  // 2) forward rfft along w via MFMA (unnormalized), bf16 out
  k_rfft_w_mfma<<<dim3(BATCH*HH, DIM/96), 256, 0, stream>>>(Xb, Sr, Si);
  // 3-5) FUSED: fft_h -> block MLP -> ifft_h (r6 structure, bf16 IO)
  k_fmix<<<dim3(BATCH*KH, NBLK), 256, 0, stream>>>(Sr, Si, WT, b1, b2, b2x);
  // 6) c2r inverse along k via MFMA + bias add -> final fp32 output
  k_irfft_w_mfma<<<dim3(BATCH*HH, DIM/96), 256, 0, stream>>>(Sr, Si, Bias, out);
}